// Round 4
// baseline (881.838 us; speedup 1.0000x reference)
//
#include <hip/hip_runtime.h>
#include <hip/hip_bf16.h>
#include <math.h>

#define NN   50000
#define EE   800000
#define ETOT (EE + NN)
#define KDIM 256
#define HEADS 4
#define HIDD 64

typedef float  f32x4  __attribute__((ext_vector_type(4)));
typedef short  bf16x8 __attribute__((ext_vector_type(8)));

__device__ __forceinline__ float b2f(unsigned short u) {
    union { float f; unsigned int i; } v; v.i = (unsigned int)u << 16; return v.f;
}
__device__ __forceinline__ unsigned short f2b(float f) {
    union { float f; unsigned int i; } v; v.f = f;
    return (unsigned short)((v.i + 0x7fffu + ((v.i >> 16) & 1u)) >> 16);
}
__device__ __forceinline__ float lrelu(float x) { return x >= 0.f ? x : 0.2f * x; }

// ---------------------------------------------------------------------------
// fp32 -> bf16 cast, 4 elems/thread. n multiple of 4.
// ---------------------------------------------------------------------------
__global__ __launch_bounds__(256) void cast_k(
    const float* __restrict__ in, unsigned short* __restrict__ out, int n)
{
    int i = (blockIdx.x * 256 + threadIdx.x) * 4;
    if (i >= n) return;
    float4 v = *reinterpret_cast<const float4*>(in + i);
    ushort4 o;
    o.x = f2b(v.x); o.y = f2b(v.y); o.z = f2b(v.z); o.w = f2b(v.w);
    *reinterpret_cast<ushort4*>(out + i) = o;
}

// ---------------------------------------------------------------------------
// bf16 MFMA GEMM (TN): C[m][c] = sum_k A[m][k]*W[c][k], K=256, ncols=256.
// One wave per 16-row tile, 16 col-tiles. 4 waves/block.
// ---------------------------------------------------------------------------
__global__ __launch_bounds__(256) void gemm_mfma(
    const unsigned short* __restrict__ A, const unsigned short* __restrict__ W,
    unsigned short* __restrict__ C, int Mrows)
{
    int wid  = threadIdx.x >> 6;
    int lane = threadIdx.x & 63;
    int m0 = (blockIdx.x * 4 + wid) * 16;
    if (m0 >= Mrows) return;
    int cl = lane & 15;
    int kg = lane >> 4;

    int arow = m0 + cl; if (arow >= Mrows) arow = Mrows - 1;
    const unsigned short* ap = A + (size_t)arow * KDIM + kg * 8;

    f32x4 acc[16];
    #pragma unroll
    for (int ct = 0; ct < 16; ct++) acc[ct] = (f32x4)(0.f);

    for (int k0 = 0; k0 < KDIM; k0 += 32) {
        bf16x8 a = *reinterpret_cast<const bf16x8*>(ap + k0);
        #pragma unroll
        for (int ct = 0; ct < 16; ct++) {
            bf16x8 b = *reinterpret_cast<const bf16x8*>(
                W + (size_t)(ct * 16 + cl) * KDIM + k0 + kg * 8);
            acc[ct] = __builtin_amdgcn_mfma_f32_16x16x32_bf16(a, b, acc[ct], 0, 0, 0);
        }
    }

    #pragma unroll
    for (int ct = 0; ct < 16; ct++) {
        #pragma unroll
        for (int r = 0; r < 4; r++) {
            int n = m0 + kg * 4 + r;
            if (n < Mrows)
                C[(size_t)n * KDIM + ct * 16 + cl] = f2b(acc[ct][r]);
        }
    }
}

// ---------------------------------------------------------------------------
// Per-node attention terms from bf16 H.
// ---------------------------------------------------------------------------
__global__ __launch_bounds__(256) void alphas_k(
    const unsigned short* __restrict__ H, const float* __restrict__ a_src,
    const float* __restrict__ a_dst, float* __restrict__ AS, float* __restrict__ AD)
{
    int wave = threadIdx.x >> 6;
    int lane = threadIdx.x & 63;
    int n = blockIdx.x * 4 + wave;
    if (n >= NN) return;
    const unsigned short* hrow = H + (size_t)n * 256;
    #pragma unroll
    for (int h = 0; h < HEADS; h++) {
        float v = b2f(hrow[h * 64 + lane]);
        float s = v * a_src[h * 64 + lane];
        float d = v * a_dst[h * 64 + lane];
        #pragma unroll
        for (int m = 32; m >= 1; m >>= 1) {
            s += __shfl_xor(s, m, 64);
            d += __shfl_xor(d, m, 64);
        }
        if (lane == 0) { AS[n * 4 + h] = s; AD[n * 4 + h] = d; }
    }
}

// ---------------------------------------------------------------------------
// CSR build
// ---------------------------------------------------------------------------
__global__ __launch_bounds__(256) void zero_deg_k(int* __restrict__ deg)
{
    int i = blockIdx.x * 256 + threadIdx.x;
    if (i < NN) deg[i] = 0;
}

__global__ __launch_bounds__(256) void count_deg_k(const int* __restrict__ ei, int* __restrict__ deg)
{
    int e = blockIdx.x * 256 + threadIdx.x;
    if (e >= ETOT) return;
    int dst = (e < EE) ? ei[EE + e] : e - EE;
    atomicAdd(deg + dst, 1);
}

#define CHUNK 196   // 256*196 = 50176 >= NN

__global__ __launch_bounds__(256) void scan_k(
    const int* __restrict__ deg, int* __restrict__ rowptr, int* __restrict__ cursor)
{
    __shared__ int pref[256];
    int t = threadIdx.x;
    int beg = t * CHUNK, end = min(beg + CHUNK, NN);
    int s = 0;
    for (int i = beg; i < end; i++) s += deg[i];
    pref[t] = s;
    __syncthreads();
    if (t == 0) {
        int run = 0;
        for (int i = 0; i < 256; i++) { int v = pref[i]; pref[i] = run; run += v; }
    }
    __syncthreads();
    int run = pref[t];
    for (int i = beg; i < end; i++) {
        rowptr[i] = run;
        cursor[i] = run;
        run += deg[i];
    }
    if (t == 255) rowptr[NN] = ETOT;
}

__global__ __launch_bounds__(256) void fill_k(
    const int* __restrict__ ei, int* __restrict__ cursor,
    int* __restrict__ EDG, int* __restrict__ DSTOF)
{
    int e = blockIdx.x * 256 + threadIdx.x;
    if (e >= ETOT) return;
    int src, dst;
    if (e < EE) { src = ei[e]; dst = ei[EE + e]; }
    else        { src = dst = e - EE; }
    int pos = atomicAdd(cursor + dst, 1);
    EDG[pos] = src;
    DSTOF[pos] = dst;
}

// ---------------------------------------------------------------------------
// Per-edge logits in CSR order, 4 planes: LOG[h*ETOT+e] = lrelu(AS[src][h]+AD[dst][h])
// ---------------------------------------------------------------------------
__global__ __launch_bounds__(256) void elog_k(
    const int* __restrict__ EDG, const int* __restrict__ DSTOF,
    const float* __restrict__ AS, const float* __restrict__ AD,
    float* __restrict__ LOG)
{
    int e = blockIdx.x * 256 + threadIdx.x;
    if (e >= ETOT) return;
    int src = EDG[e], dst = DSTOF[e];
    float4 s4 = *reinterpret_cast<const float4*>(AS + (size_t)src * 4);
    float4 d4 = *reinterpret_cast<const float4*>(AD + (size_t)dst * 4);
    LOG[0 * (size_t)ETOT + e] = lrelu(s4.x + d4.x);
    LOG[1 * (size_t)ETOT + e] = lrelu(s4.y + d4.y);
    LOG[2 * (size_t)ETOT + e] = lrelu(s4.z + d4.z);
    LOG[3 * (size_t)ETOT + e] = lrelu(s4.w + d4.w);
}

// ---------------------------------------------------------------------------
// Head-split gather. One wave = (node, head); lane = feature (64 per head).
// head = blockIdx.x & 3  -> with round-robin block->XCD dispatch, each head's
// 6.4 MB H-slice localizes to 2 XCDs' L2s.
// Fast path deg<=64: lane l owns edge l (logit, src); softmax via shfl;
// H loads independent (srcs known upfront).
// MODE 1: OUT(bf16)[n][h*64+l] = relu(acc/den + bias).
// MODE 2: PART(bf16)[n][h*64+l] = 0.25*acc/den (summed by sum4_k).
// ---------------------------------------------------------------------------
#define NINF (-__builtin_inff())

template<int MODE>
__global__ __launch_bounds__(256) void gather_k(
    const int* __restrict__ rowptr, const int* __restrict__ EDG,
    const float* __restrict__ LOG, const unsigned short* __restrict__ H,
    const float* __restrict__ bias, unsigned short* __restrict__ OUT)
{
    int wid  = threadIdx.x >> 6;
    int lane = threadIdx.x & 63;
    int head = blockIdx.x & 3;
    int n = (blockIdx.x >> 2) * 4 + wid;
    if (n >= NN) return;

    int beg = rowptr[n], end = rowptr[n + 1];
    int deg = end - beg;
    const float* lp = LOG + (size_t)head * ETOT + beg;
    const unsigned short* hp = H + head * 64 + lane;

    float acc = 0.f, den;

    if (deg <= 64) {
        int   srcv = (lane < deg) ? EDG[beg + lane] : 0;
        float lg   = (lane < deg) ? lp[lane] : NINF;
        float m = lg;
        #pragma unroll
        for (int msk = 1; msk <= 32; msk <<= 1) m = fmaxf(m, __shfl_xor(m, msk, 64));
        float w = (lane < deg) ? __expf(lg - m) : 0.f;
        float s = w;
        #pragma unroll
        for (int msk = 1; msk <= 32; msk <<= 1) s += __shfl_xor(s, msk, 64);
        den = s;
        for (int j = 0; j < deg; j++) {
            int   src = __shfl(srcv, j, 64);
            float wj  = __shfl(w, j, 64);
            acc += wj * b2f(hp[(size_t)src * 256]);
        }
    } else {
        // generic chunked path (rare)
        float m = NINF;
        for (int b = beg; b < end; b += 64) {
            int l = b + lane;
            float lg = (l < end) ? LOG[(size_t)head * ETOT + l] : NINF;
            m = fmaxf(m, lg);
        }
        #pragma unroll
        for (int msk = 1; msk <= 32; msk <<= 1) m = fmaxf(m, __shfl_xor(m, msk, 64));
        float s = 0.f;
        for (int b = beg; b < end; b += 64) {
            int l = b + lane;
            int cd = min(end - b, 64);
            int   srcv = (lane < cd) ? EDG[b + lane] : 0;
            float lg   = (lane < cd) ? LOG[(size_t)head * ETOT + l] : NINF;
            float w    = (lane < cd) ? __expf(lg - m) : 0.f;
            s += w;
            for (int j = 0; j < cd; j++) {
                int   src = __shfl(srcv, j, 64);
                float wj  = __shfl(w, j, 64);
                acc += wj * b2f(hp[(size_t)src * 256]);
            }
        }
        #pragma unroll
        for (int msk = 1; msk <= 32; msk <<= 1) s += __shfl_xor(s, msk, 64);
        den = s;
    }

    float inv = 1.f / den;   // self-loop guarantees den > 0
    if (MODE == 1) {
        float v = fmaxf(acc * inv + bias[head * 64 + lane], 0.f);
        OUT[(size_t)n * 256 + head * 64 + lane] = f2b(v);
    } else {
        OUT[(size_t)n * 256 + head * 64 + lane] = f2b(0.25f * acc * inv);
    }
}

// ---------------------------------------------------------------------------
// out[n][c] += sum_h PART[n][h*64+c]   (out already holds root skip + biases)
// ---------------------------------------------------------------------------
__global__ __launch_bounds__(256) void sum4_k(
    const unsigned short* __restrict__ PART, float* __restrict__ out)
{
    int i = blockIdx.x * 256 + threadIdx.x;   // i = n*64 + c
    if (i >= NN * 64) return;
    int n = i >> 6, c = i & 63;
    const unsigned short* p = PART + (size_t)n * 256 + c;
    out[i] += b2f(p[0]) + b2f(p[64]) + b2f(p[128]) + b2f(p[192]);
}

// ---------------------------------------------------------------------------
// fp32 vector GEMM for the root skip (64 cols): OUT = root@Wr.T + br + b2.
// ---------------------------------------------------------------------------
#define BM 64
#define BN 64
#define BKT 64

__global__ __launch_bounds__(256) void gemm_tn(
    const float* __restrict__ A, const float* __restrict__ W,
    float* __restrict__ C, int Mrows, int ncols,
    const float* __restrict__ bias0, const float* __restrict__ bias1)
{
    __shared__ float As[BKT][BM + 4];
    __shared__ float Bs[BKT][BN + 4];

    const int tid = threadIdx.x;
    const int rg = tid >> 4;
    const int cg = tid & 15;
    const int n0 = blockIdx.x * BM;
    const int c0 = blockIdx.y * BN;

    float acc[4][4];
    #pragma unroll
    for (int i = 0; i < 4; i++)
        #pragma unroll
        for (int j = 0; j < 4; j++) acc[i][j] = 0.f;

    for (int k0 = 0; k0 < KDIM; k0 += BKT) {
        #pragma unroll
        for (int i = 0; i < 4; i++) {
            int f  = tid + 256 * i;
            int r  = f >> 4;
            int kq = f & 15;
            float4 v = make_float4(0.f, 0.f, 0.f, 0.f);
            int gr = n0 + r;
            if (gr < Mrows)
                v = *reinterpret_cast<const float4*>(A + (size_t)gr * KDIM + k0 + kq * 4);
            As[kq * 4 + 0][r] = v.x;
            As[kq * 4 + 1][r] = v.y;
            As[kq * 4 + 2][r] = v.z;
            As[kq * 4 + 3][r] = v.w;
        }
        #pragma unroll
        for (int i = 0; i < 4; i++) {
            int f  = tid + 256 * i;
            int c  = f >> 4;
            int kq = f & 15;
            float4 v = *reinterpret_cast<const float4*>(W + (size_t)(c0 + c) * KDIM + k0 + kq * 4);
            Bs[kq * 4 + 0][c] = v.x;
            Bs[kq * 4 + 1][c] = v.y;
            Bs[kq * 4 + 2][c] = v.z;
            Bs[kq * 4 + 3][c] = v.w;
        }
        __syncthreads();

        #pragma unroll 16
        for (int k = 0; k < BKT; k++) {
            float4 a = *reinterpret_cast<const float4*>(&As[k][rg * 4]);
            float4 b = *reinterpret_cast<const float4*>(&Bs[k][cg * 4]);
            acc[0][0] += a.x * b.x; acc[0][1] += a.x * b.y; acc[0][2] += a.x * b.z; acc[0][3] += a.x * b.w;
            acc[1][0] += a.y * b.x; acc[1][1] += a.y * b.y; acc[1][2] += a.y * b.z; acc[1][3] += a.y * b.w;
            acc[2][0] += a.z * b.x; acc[2][1] += a.z * b.y; acc[2][2] += a.z * b.z; acc[2][3] += a.z * b.w;
            acc[3][0] += a.w * b.x; acc[3][1] += a.w * b.y; acc[3][2] += a.w * b.z; acc[3][3] += a.w * b.w;
        }
        __syncthreads();
    }

    #pragma unroll
    for (int i = 0; i < 4; i++) {
        int gr = n0 + rg * 4 + i;
        if (gr >= Mrows) continue;
        float4 v = make_float4(acc[i][0], acc[i][1], acc[i][2], acc[i][3]);
        int gc = c0 + cg * 4;
        if (bias0) { v.x += bias0[gc + 0]; v.y += bias0[gc + 1]; v.z += bias0[gc + 2]; v.w += bias0[gc + 3]; }
        if (bias1) { v.x += bias1[gc + 0]; v.y += bias1[gc + 1]; v.z += bias1[gc + 2]; v.w += bias1[gc + 3]; }
        *reinterpret_cast<float4*>(C + (size_t)gr * ncols + gc) = v;
    }
}

// ---------------------------------------------------------------------------
extern "C" void kernel_launch(void* const* d_in, const int* in_sizes, int n_in,
                              void* d_out, int out_size, void* d_ws, size_t ws_size,
                              hipStream_t stream) {
    const float* x    = (const float*)d_in[0];
    const float* root = (const float*)d_in[1];
    const int*   ei   = (const int*)  d_in[2];
    const float* W1   = (const float*)d_in[3];
    const float* as1  = (const float*)d_in[4];
    const float* ad1  = (const float*)d_in[5];
    const float* b1   = (const float*)d_in[6];
    const float* W2   = (const float*)d_in[7];
    const float* as2  = (const float*)d_in[8];
    const float* ad2  = (const float*)d_in[9];
    const float* b2   = (const float*)d_in[10];
    const float* Wr   = (const float*)d_in[11];
    const float* br   = (const float*)d_in[12];
    float* out = (float*)d_out;

    unsigned short* xb  = (unsigned short*)d_ws;             // N*256 (reused as PART)
    unsigned short* Hb  = xb  + (size_t)NN * 256;            // N*256
    unsigned short* X2b = Hb  + (size_t)NN * 256;            // N*256
    unsigned short* w1b = X2b + (size_t)NN * 256;            // 65536
    unsigned short* w2b = w1b + 65536;                       // 65536
    float* AS  = (float*)(w2b + 65536);                      // N*4
    float* AD  = AS + (size_t)NN * 4;                        // N*4
    float* LOG = AD + (size_t)NN * 4;                        // 4*ETOT
    int*   deg    = (int*)(LOG + 4 * (size_t)ETOT);          // N
    int*   rowptr = deg + NN;                                // N+1
    int*   cursor = rowptr + NN + 1;                         // N
    int*   EDG    = cursor + NN;                             // ETOT
    int*   DSTOF  = EDG + ETOT;                              // ETOT

    const int egrid = (ETOT + 255) / 256;
    const int ngrid = (NN + 255) / 256;
    const int wgrid = (NN + 3) / 4;
    const int mgrid = (NN + 63) / 64;
    const int ggrid = ((NN + 3) / 4) * 4;     // (node-groups) x 4 heads

    // ----- CSR build -----
    zero_deg_k<<<ngrid, 256, 0, stream>>>(deg);
    count_deg_k<<<egrid, 256, 0, stream>>>(ei, deg);
    scan_k<<<1, 256, 0, stream>>>(deg, rowptr, cursor);
    fill_k<<<egrid, 256, 0, stream>>>(ei, cursor, EDG, DSTOF);

    // ----- casts -----
    cast_k<<<(NN * 256 / 4 + 255) / 256, 256, 0, stream>>>(x, xb, NN * 256);
    cast_k<<<(65536 / 4 + 255) / 256, 256, 0, stream>>>(W1, w1b, 65536);
    cast_k<<<(65536 / 4 + 255) / 256, 256, 0, stream>>>(W2, w2b, 65536);

    // ----- layer 1 -----
    gemm_mfma<<<mgrid, 256, 0, stream>>>(xb, w1b, Hb, NN);
    alphas_k<<<wgrid, 256, 0, stream>>>(Hb, as1, ad1, AS, AD);
    elog_k<<<egrid, 256, 0, stream>>>(EDG, DSTOF, AS, AD, LOG);
    gather_k<1><<<ggrid, 256, 0, stream>>>(rowptr, EDG, LOG, Hb, b1, X2b);

    // ----- layer 2 -----
    gemm_mfma<<<mgrid, 256, 0, stream>>>(X2b, w2b, Hb, NN);
    alphas_k<<<wgrid, 256, 0, stream>>>(Hb, as2, ad2, AS, AD);
    elog_k<<<egrid, 256, 0, stream>>>(EDG, DSTOF, AS, AD, LOG);

    // root skip + biases into d_out (fp32), then head-split partials + sum
    gemm_tn<<<dim3((NN + BM - 1) / BM, 1), 256, 0, stream>>>(root, Wr, out, NN, 64, br, b2);
    gather_k<2><<<ggrid, 256, 0, stream>>>(rowptr, EDG, LOG, Hb, nullptr, xb /*PART*/);
    sum4_k<<<(NN * 64 + 255) / 256, 256, 0, stream>>>(xb, out);
}

// Round 5
// 621.467 us; speedup vs baseline: 1.4190x; 1.4190x over previous
//
#include <hip/hip_runtime.h>
#include <hip/hip_bf16.h>
#include <math.h>

#define NN   50000
#define EE   800000
#define ETOT (EE + NN)
#define KDIM 256
#define HEADS 4
#define HIDD 64

typedef float  f32x4  __attribute__((ext_vector_type(4)));
typedef short  bf16x8 __attribute__((ext_vector_type(8)));

__device__ __forceinline__ float b2f(unsigned short u) {
    union { float f; unsigned int i; } v; v.i = (unsigned int)u << 16; return v.f;
}
__device__ __forceinline__ unsigned short f2b(float f) {
    union { float f; unsigned int i; } v; v.f = f;
    return (unsigned short)((v.i + 0x7fffu + ((v.i >> 16) & 1u)) >> 16);
}
__device__ __forceinline__ float lrelu(float x) { return x >= 0.f ? x : 0.2f * x; }

#define NINF (-__builtin_inff())

// ---------------------------------------------------------------------------
// fp32 -> bf16 cast, 4 elems/thread. n multiple of 4.
// ---------------------------------------------------------------------------
__global__ __launch_bounds__(256) void cast_k(
    const float* __restrict__ in, unsigned short* __restrict__ out, int n)
{
    int i = (blockIdx.x * 256 + threadIdx.x) * 4;
    if (i >= n) return;
    float4 v = *reinterpret_cast<const float4*>(in + i);
    ushort4 o;
    o.x = f2b(v.x); o.y = f2b(v.y); o.z = f2b(v.z); o.w = f2b(v.w);
    *reinterpret_cast<ushort4*>(out + i) = o;
}

// ---------------------------------------------------------------------------
// bf16 MFMA GEMM (TN): C[m][c] = sum_k A[m][k]*W[c][k], K=256, ncols=256.
// One wave per 16-row tile, 16 col-tiles. 4 waves/block.
// ---------------------------------------------------------------------------
__global__ __launch_bounds__(256) void gemm_mfma(
    const unsigned short* __restrict__ A, const unsigned short* __restrict__ W,
    unsigned short* __restrict__ C, int Mrows)
{
    int wid  = threadIdx.x >> 6;
    int lane = threadIdx.x & 63;
    int m0 = (blockIdx.x * 4 + wid) * 16;
    if (m0 >= Mrows) return;
    int cl = lane & 15;
    int kg = lane >> 4;

    int arow = m0 + cl; if (arow >= Mrows) arow = Mrows - 1;
    const unsigned short* ap = A + (size_t)arow * KDIM + kg * 8;

    f32x4 acc[16];
    #pragma unroll
    for (int ct = 0; ct < 16; ct++) acc[ct] = (f32x4)(0.f);

    for (int k0 = 0; k0 < KDIM; k0 += 32) {
        bf16x8 a = *reinterpret_cast<const bf16x8*>(ap + k0);
        #pragma unroll
        for (int ct = 0; ct < 16; ct++) {
            bf16x8 b = *reinterpret_cast<const bf16x8*>(
                W + (size_t)(ct * 16 + cl) * KDIM + k0 + kg * 8);
            acc[ct] = __builtin_amdgcn_mfma_f32_16x16x32_bf16(a, b, acc[ct], 0, 0, 0);
        }
    }

    #pragma unroll
    for (int ct = 0; ct < 16; ct++) {
        #pragma unroll
        for (int r = 0; r < 4; r++) {
            int n = m0 + kg * 4 + r;
            if (n < Mrows)
                C[(size_t)n * KDIM + ct * 16 + cl] = f2b(acc[ct][r]);
        }
    }
}

// ---------------------------------------------------------------------------
// Per-node attention terms from bf16 H.
// ---------------------------------------------------------------------------
__global__ __launch_bounds__(256) void alphas_k(
    const unsigned short* __restrict__ H, const float* __restrict__ a_src,
    const float* __restrict__ a_dst, float* __restrict__ AS, float* __restrict__ AD)
{
    int wave = threadIdx.x >> 6;
    int lane = threadIdx.x & 63;
    int n = blockIdx.x * 4 + wave;
    if (n >= NN) return;
    const unsigned short* hrow = H + (size_t)n * 256;
    #pragma unroll
    for (int h = 0; h < HEADS; h++) {
        float v = b2f(hrow[h * 64 + lane]);
        float s = v * a_src[h * 64 + lane];
        float d = v * a_dst[h * 64 + lane];
        #pragma unroll
        for (int m = 32; m >= 1; m >>= 1) {
            s += __shfl_xor(s, m, 64);
            d += __shfl_xor(d, m, 64);
        }
        if (lane == 0) { AS[n * 4 + h] = s; AD[n * 4 + h] = d; }
    }
}

// ---------------------------------------------------------------------------
// CSR build
// ---------------------------------------------------------------------------
__global__ __launch_bounds__(256) void zero_deg_k(int* __restrict__ deg)
{
    int i = blockIdx.x * 256 + threadIdx.x;
    if (i < NN) deg[i] = 0;
}

__global__ __launch_bounds__(256) void count_deg_k(const int* __restrict__ ei, int* __restrict__ deg)
{
    int e = blockIdx.x * 256 + threadIdx.x;
    if (e >= ETOT) return;
    int dst = (e < EE) ? ei[EE + e] : e - EE;
    atomicAdd(deg + dst, 1);
}

#define CHUNK 196   // 256*196 = 50176 >= NN

__global__ __launch_bounds__(256) void scan_k(
    const int* __restrict__ deg, int* __restrict__ rowptr, int* __restrict__ cursor)
{
    __shared__ int pref[256];
    int t = threadIdx.x;
    int beg = t * CHUNK, end = min(beg + CHUNK, NN);
    int s = 0;
    for (int i = beg; i < end; i++) s += deg[i];
    pref[t] = s;
    __syncthreads();
    if (t == 0) {
        int run = 0;
        for (int i = 0; i < 256; i++) { int v = pref[i]; pref[i] = run; run += v; }
    }
    __syncthreads();
    int run = pref[t];
    for (int i = beg; i < end; i++) {
        rowptr[i] = run;
        cursor[i] = run;
        run += deg[i];
    }
    if (t == 255) rowptr[NN] = ETOT;
}

__global__ __launch_bounds__(256) void fill_k(
    const int* __restrict__ ei, int* __restrict__ cursor,
    int* __restrict__ EDG, int* __restrict__ DSTOF)
{
    int e = blockIdx.x * 256 + threadIdx.x;
    if (e >= ETOT) return;
    int src, dst;
    if (e < EE) { src = ei[e]; dst = ei[EE + e]; }
    else        { src = dst = e - EE; }
    int pos = atomicAdd(cursor + dst, 1);
    EDG[pos] = src;
    DSTOF[pos] = dst;
}

// ---------------------------------------------------------------------------
// Per-edge logits in CSR order, interleaved float4 (one per edge, 4 heads).
// ---------------------------------------------------------------------------
__global__ __launch_bounds__(256) void elog_k(
    const int* __restrict__ EDG, const int* __restrict__ DSTOF,
    const float* __restrict__ AS, const float* __restrict__ AD,
    float4* __restrict__ LOG4)
{
    int e = blockIdx.x * 256 + threadIdx.x;
    if (e >= ETOT) return;
    int src = EDG[e], dst = DSTOF[e];
    float4 s4 = *reinterpret_cast<const float4*>(AS + (size_t)src * 4);
    float4 d4 = *reinterpret_cast<const float4*>(AD + (size_t)dst * 4);
    LOG4[e] = make_float4(lrelu(s4.x + d4.x), lrelu(s4.y + d4.y),
                          lrelu(s4.z + d4.z), lrelu(s4.w + d4.w));
}

// ---------------------------------------------------------------------------
// Gather-aggregate. One wave per node (4/block). Lane l: feats l*4..l*4+3,
// head = l>>4. Chunked over edges (chunk = 64):
//   lane owns edge (chunk+lane): loads float4 logits, shfl-reduce max/denom
//   for all 4 heads at once; normalized weights go to a per-wave LDS table
//   (padded stride 65 -> 4 distinct banks); inner loop broadcasts src via
//   v_readlane (SGPR base -> scalar-addressed dwordx2 H loads, all independent).
// MODE 1: OUT(bf16)[n][c] = relu(acc/den + bias).
// MODE 2: OUTF(f32)[n][c64] += 0.25 * sum_h acc_h/den_h  (root skip already in OUTF).
// ---------------------------------------------------------------------------
template<int MODE>
__global__ __launch_bounds__(256) void gather_k(
    const int* __restrict__ rowptr, const int* __restrict__ EDG,
    const float4* __restrict__ LOG4, const unsigned short* __restrict__ H,
    const float* __restrict__ bias, unsigned short* __restrict__ OUT,
    float* __restrict__ OUTF)
{
    __shared__ float wT[4][4][65];   // [wave][head][edge-in-chunk], pad->4 banks
    int wid  = threadIdx.x >> 6;
    int lane = threadIdx.x & 63;
    int n = blockIdx.x * 4 + wid;
    if (n >= NN) return;
    int head = lane >> 4;

    int beg = rowptr[n], end = rowptr[n + 1];

    // ---- pass 1: per-head max over edges ----
    float4 m4 = make_float4(NINF, NINF, NINF, NINF);
    for (int b = beg; b < end; b += 64) {
        int l = b + lane;
        if (l < end) {
            float4 lg = LOG4[l];
            m4.x = fmaxf(m4.x, lg.x); m4.y = fmaxf(m4.y, lg.y);
            m4.z = fmaxf(m4.z, lg.z); m4.w = fmaxf(m4.w, lg.w);
        }
    }
    #pragma unroll
    for (int msk = 1; msk <= 32; msk <<= 1) {
        m4.x = fmaxf(m4.x, __shfl_xor(m4.x, msk, 64));
        m4.y = fmaxf(m4.y, __shfl_xor(m4.y, msk, 64));
        m4.z = fmaxf(m4.z, __shfl_xor(m4.z, msk, 64));
        m4.w = fmaxf(m4.w, __shfl_xor(m4.w, msk, 64));
    }

    // ---- pass 2: weights + weighted feature accumulation ----
    float4 den4 = make_float4(0.f, 0.f, 0.f, 0.f);
    float a0 = 0.f, a1 = 0.f, a2 = 0.f, a3 = 0.f;
    const unsigned short* hp = H + lane * 4;

    for (int b = beg; b < end; b += 64) {
        int cd = min(end - b, 64);
        int srcv = (lane < cd) ? EDG[b + lane] : 0;
        float4 w4 = make_float4(0.f, 0.f, 0.f, 0.f);
        if (lane < cd) {
            float4 lg = LOG4[b + lane];
            w4.x = __expf(lg.x - m4.x); w4.y = __expf(lg.y - m4.y);
            w4.z = __expf(lg.z - m4.z); w4.w = __expf(lg.w - m4.w);
        }
        den4.x += w4.x; den4.y += w4.y; den4.z += w4.z; den4.w += w4.w;
        wT[wid][0][lane] = w4.x;
        wT[wid][1][lane] = w4.y;
        wT[wid][2][lane] = w4.z;
        wT[wid][3][lane] = w4.w;
        // same-wave LDS write->read: compiler inserts lgkmcnt wait
        for (int j = 0; j < cd; j++) {
            int   src = __builtin_amdgcn_readlane(srcv, j);
            float wj  = wT[wid][head][j];
            ushort4 hv = *reinterpret_cast<const ushort4*>(hp + (size_t)src * 256);
            a0 += wj * b2f(hv.x); a1 += wj * b2f(hv.y);
            a2 += wj * b2f(hv.z); a3 += wj * b2f(hv.w);
        }
    }

    #pragma unroll
    for (int msk = 1; msk <= 32; msk <<= 1) {
        den4.x += __shfl_xor(den4.x, msk, 64);
        den4.y += __shfl_xor(den4.y, msk, 64);
        den4.z += __shfl_xor(den4.z, msk, 64);
        den4.w += __shfl_xor(den4.w, msk, 64);
    }
    float den = head == 0 ? den4.x : head == 1 ? den4.y : head == 2 ? den4.z : den4.w;
    float inv = 1.f / den;   // self-loop guarantees den > 0

    if (MODE == 1) {
        float4 bv = *reinterpret_cast<const float4*>(bias + lane * 4);
        ushort4 o;
        o.x = f2b(fmaxf(a0 * inv + bv.x, 0.f));
        o.y = f2b(fmaxf(a1 * inv + bv.y, 0.f));
        o.z = f2b(fmaxf(a2 * inv + bv.z, 0.f));
        o.w = f2b(fmaxf(a3 * inv + bv.w, 0.f));
        *reinterpret_cast<ushort4*>(OUT + (size_t)n * 256 + lane * 4) = o;
    } else {
        float v0 = a0 * inv, v1 = a1 * inv, v2 = a2 * inv, v3 = a3 * inv;
        #pragma unroll
        for (int msk = 16; msk <= 32; msk <<= 1) {
            v0 += __shfl_xor(v0, msk, 64);
            v1 += __shfl_xor(v1, msk, 64);
            v2 += __shfl_xor(v2, msk, 64);
            v3 += __shfl_xor(v3, msk, 64);
        }
        if (lane < 16) {
            float4* o = reinterpret_cast<float4*>(OUTF + (size_t)n * 64 + lane * 4);
            float4 cur = *o;
            cur.x += 0.25f * v0;
            cur.y += 0.25f * v1;
            cur.z += 0.25f * v2;
            cur.w += 0.25f * v3;
            *o = cur;
        }
    }
}

// ---------------------------------------------------------------------------
// fp32 vector GEMM for the root skip (64 cols): OUT = root@Wr.T + br + b2.
// ---------------------------------------------------------------------------
#define BM 64
#define BN 64
#define BKT 64

__global__ __launch_bounds__(256) void gemm_tn(
    const float* __restrict__ A, const float* __restrict__ W,
    float* __restrict__ C, int Mrows, int ncols,
    const float* __restrict__ bias0, const float* __restrict__ bias1)
{
    __shared__ float As[BKT][BM + 4];
    __shared__ float Bs[BKT][BN + 4];

    const int tid = threadIdx.x;
    const int rg = tid >> 4;
    const int cg = tid & 15;
    const int n0 = blockIdx.x * BM;
    const int c0 = blockIdx.y * BN;

    float acc[4][4];
    #pragma unroll
    for (int i = 0; i < 4; i++)
        #pragma unroll
        for (int j = 0; j < 4; j++) acc[i][j] = 0.f;

    for (int k0 = 0; k0 < KDIM; k0 += BKT) {
        #pragma unroll
        for (int i = 0; i < 4; i++) {
            int f  = tid + 256 * i;
            int r  = f >> 4;
            int kq = f & 15;
            float4 v = make_float4(0.f, 0.f, 0.f, 0.f);
            int gr = n0 + r;
            if (gr < Mrows)
                v = *reinterpret_cast<const float4*>(A + (size_t)gr * KDIM + k0 + kq * 4);
            As[kq * 4 + 0][r] = v.x;
            As[kq * 4 + 1][r] = v.y;
            As[kq * 4 + 2][r] = v.z;
            As[kq * 4 + 3][r] = v.w;
        }
        #pragma unroll
        for (int i = 0; i < 4; i++) {
            int f  = tid + 256 * i;
            int c  = f >> 4;
            int kq = f & 15;
            float4 v = *reinterpret_cast<const float4*>(W + (size_t)(c0 + c) * KDIM + k0 + kq * 4);
            Bs[kq * 4 + 0][c] = v.x;
            Bs[kq * 4 + 1][c] = v.y;
            Bs[kq * 4 + 2][c] = v.z;
            Bs[kq * 4 + 3][c] = v.w;
        }
        __syncthreads();

        #pragma unroll 16
        for (int k = 0; k < BKT; k++) {
            float4 a = *reinterpret_cast<const float4*>(&As[k][rg * 4]);
            float4 b = *reinterpret_cast<const float4*>(&Bs[k][cg * 4]);
            acc[0][0] += a.x * b.x; acc[0][1] += a.x * b.y; acc[0][2] += a.x * b.z; acc[0][3] += a.x * b.w;
            acc[1][0] += a.y * b.x; acc[1][1] += a.y * b.y; acc[1][2] += a.y * b.z; acc[1][3] += a.y * b.w;
            acc[2][0] += a.z * b.x; acc[2][1] += a.z * b.y; acc[2][2] += a.z * b.z; acc[2][3] += a.z * b.w;
            acc[3][0] += a.w * b.x; acc[3][1] += a.w * b.y; acc[3][2] += a.w * b.z; acc[3][3] += a.w * b.w;
        }
        __syncthreads();
    }

    #pragma unroll
    for (int i = 0; i < 4; i++) {
        int gr = n0 + rg * 4 + i;
        if (gr >= Mrows) continue;
        float4 v = make_float4(acc[i][0], acc[i][1], acc[i][2], acc[i][3]);
        int gc = c0 + cg * 4;
        if (bias0) { v.x += bias0[gc + 0]; v.y += bias0[gc + 1]; v.z += bias0[gc + 2]; v.w += bias0[gc + 3]; }
        if (bias1) { v.x += bias1[gc + 0]; v.y += bias1[gc + 1]; v.z += bias1[gc + 2]; v.w += bias1[gc + 3]; }
        *reinterpret_cast<float4*>(C + (size_t)gr * ncols + gc) = v;
    }
}

// ---------------------------------------------------------------------------
extern "C" void kernel_launch(void* const* d_in, const int* in_sizes, int n_in,
                              void* d_out, int out_size, void* d_ws, size_t ws_size,
                              hipStream_t stream) {
    const float* x    = (const float*)d_in[0];
    const float* root = (const float*)d_in[1];
    const int*   ei   = (const int*)  d_in[2];
    const float* W1   = (const float*)d_in[3];
    const float* as1  = (const float*)d_in[4];
    const float* ad1  = (const float*)d_in[5];
    const float* b1   = (const float*)d_in[6];
    const float* W2   = (const float*)d_in[7];
    const float* as2  = (const float*)d_in[8];
    const float* ad2  = (const float*)d_in[9];
    const float* b2   = (const float*)d_in[10];
    const float* Wr   = (const float*)d_in[11];
    const float* br   = (const float*)d_in[12];
    float* out = (float*)d_out;

    unsigned short* xb  = (unsigned short*)d_ws;             // N*256
    unsigned short* Hb  = xb  + (size_t)NN * 256;            // N*256
    unsigned short* X2b = Hb  + (size_t)NN * 256;            // N*256
    unsigned short* w1b = X2b + (size_t)NN * 256;            // 65536
    unsigned short* w2b = w1b + 65536;                       // 65536
    float* AS  = (float*)(w2b + 65536);                      // N*4
    float* AD  = AS + (size_t)NN * 4;                        // N*4
    float4* LOG4 = (float4*)(AD + (size_t)NN * 4);           // ETOT float4
    int*   deg    = (int*)(LOG4 + (size_t)ETOT);             // N
    int*   rowptr = deg + NN;                                // N+1
    int*   cursor = rowptr + NN + 1;                         // N
    int*   EDG    = cursor + NN;                             // ETOT
    int*   DSTOF  = EDG + ETOT;                              // ETOT

    const int egrid = (ETOT + 255) / 256;
    const int ngrid = (NN + 255) / 256;
    const int wgrid = (NN + 3) / 4;
    const int mgrid = (NN + 63) / 64;

    // ----- CSR build -----
    zero_deg_k<<<ngrid, 256, 0, stream>>>(deg);
    count_deg_k<<<egrid, 256, 0, stream>>>(ei, deg);
    scan_k<<<1, 256, 0, stream>>>(deg, rowptr, cursor);
    fill_k<<<egrid, 256, 0, stream>>>(ei, cursor, EDG, DSTOF);

    // ----- casts -----
    cast_k<<<(NN * 256 / 4 + 255) / 256, 256, 0, stream>>>(x, xb, NN * 256);
    cast_k<<<(65536 / 4 + 255) / 256, 256, 0, stream>>>(W1, w1b, 65536);
    cast_k<<<(65536 / 4 + 255) / 256, 256, 0, stream>>>(W2, w2b, 65536);

    // ----- layer 1 -----
    gemm_mfma<<<mgrid, 256, 0, stream>>>(xb, w1b, Hb, NN);
    alphas_k<<<wgrid, 256, 0, stream>>>(Hb, as1, ad1, AS, AD);
    elog_k<<<egrid, 256, 0, stream>>>(EDG, DSTOF, AS, AD, LOG4);
    gather_k<1><<<wgrid, 256, 0, stream>>>(rowptr, EDG, LOG4, Hb, b1, X2b, nullptr);

    // ----- layer 2 -----
    gemm_mfma<<<mgrid, 256, 0, stream>>>(X2b, w2b, Hb, NN);
    alphas_k<<<wgrid, 256, 0, stream>>>(Hb, as2, ad2, AS, AD);
    elog_k<<<egrid, 256, 0, stream>>>(EDG, DSTOF, AS, AD, LOG4);

    // root skip + biases into d_out (fp32), then gather adds head-mean
    gemm_tn<<<dim3((NN + BM - 1) / BM, 1), 256, 0, stream>>>(root, Wr, out, NN, 64, br, b2);
    gather_k<2><<<wgrid, 256, 0, stream>>>(rowptr, EDG, LOG4, Hb, nullptr, nullptr, out);
}

// Round 6
// 516.080 us; speedup vs baseline: 1.7087x; 1.2042x over previous
//
#include <hip/hip_runtime.h>
#include <hip/hip_bf16.h>
#include <math.h>

#define NN   50000
#define EE   800000
#define ETOT (EE + NN)
#define KDIM 256
#define HEADS 4
#define HIDD 64

typedef float  f32x4  __attribute__((ext_vector_type(4)));
typedef short  bf16x8 __attribute__((ext_vector_type(8)));

__device__ __forceinline__ float b2f(unsigned short u) {
    union { float f; unsigned int i; } v; v.i = (unsigned int)u << 16; return v.f;
}
__device__ __forceinline__ unsigned short f2b(float f) {
    union { float f; unsigned int i; } v; v.f = f;
    return (unsigned short)((v.i + 0x7fffu + ((v.i >> 16) & 1u)) >> 16);
}
__device__ __forceinline__ float lrelu(float x) { return x >= 0.f ? x : 0.2f * x; }

#define NINF (-__builtin_inff())

// ---------------------------------------------------------------------------
// fp32 -> bf16 cast, 4 elems/thread. n multiple of 4.
// ---------------------------------------------------------------------------
__global__ __launch_bounds__(256) void cast_k(
    const float* __restrict__ in, unsigned short* __restrict__ out, int n)
{
    int i = (blockIdx.x * 256 + threadIdx.x) * 4;
    if (i >= n) return;
    float4 v = *reinterpret_cast<const float4*>(in + i);
    ushort4 o;
    o.x = f2b(v.x); o.y = f2b(v.y); o.z = f2b(v.z); o.w = f2b(v.w);
    *reinterpret_cast<ushort4*>(out + i) = o;
}

// ---------------------------------------------------------------------------
// bf16 MFMA GEMM (TN): C[m][c] = sum_k A[m][k]*W[c][k], K=256, ncols=256.
// One wave per 16-row tile, 16 col-tiles. 4 waves/block.
// ---------------------------------------------------------------------------
__global__ __launch_bounds__(256) void gemm_mfma(
    const unsigned short* __restrict__ A, const unsigned short* __restrict__ W,
    unsigned short* __restrict__ C, int Mrows)
{
    int wid  = threadIdx.x >> 6;
    int lane = threadIdx.x & 63;
    int m0 = (blockIdx.x * 4 + wid) * 16;
    if (m0 >= Mrows) return;
    int cl = lane & 15;
    int kg = lane >> 4;

    int arow = m0 + cl; if (arow >= Mrows) arow = Mrows - 1;
    const unsigned short* ap = A + (size_t)arow * KDIM + kg * 8;

    f32x4 acc[16];
    #pragma unroll
    for (int ct = 0; ct < 16; ct++) acc[ct] = (f32x4)(0.f);

    for (int k0 = 0; k0 < KDIM; k0 += 32) {
        bf16x8 a = *reinterpret_cast<const bf16x8*>(ap + k0);
        #pragma unroll
        for (int ct = 0; ct < 16; ct++) {
            bf16x8 b = *reinterpret_cast<const bf16x8*>(
                W + (size_t)(ct * 16 + cl) * KDIM + k0 + kg * 8);
            acc[ct] = __builtin_amdgcn_mfma_f32_16x16x32_bf16(a, b, acc[ct], 0, 0, 0);
        }
    }

    #pragma unroll
    for (int ct = 0; ct < 16; ct++) {
        #pragma unroll
        for (int r = 0; r < 4; r++) {
            int n = m0 + kg * 4 + r;
            if (n < Mrows)
                C[(size_t)n * KDIM + ct * 16 + cl] = f2b(acc[ct][r]);
        }
    }
}

// ---------------------------------------------------------------------------
// Per-node attention terms from bf16 H.
// ---------------------------------------------------------------------------
__global__ __launch_bounds__(256) void alphas_k(
    const unsigned short* __restrict__ H, const float* __restrict__ a_src,
    const float* __restrict__ a_dst, float* __restrict__ AS, float* __restrict__ AD)
{
    int wave = threadIdx.x >> 6;
    int lane = threadIdx.x & 63;
    int n = blockIdx.x * 4 + wave;
    if (n >= NN) return;
    const unsigned short* hrow = H + (size_t)n * 256;
    #pragma unroll
    for (int h = 0; h < HEADS; h++) {
        float v = b2f(hrow[h * 64 + lane]);
        float s = v * a_src[h * 64 + lane];
        float d = v * a_dst[h * 64 + lane];
        #pragma unroll
        for (int m = 32; m >= 1; m >>= 1) {
            s += __shfl_xor(s, m, 64);
            d += __shfl_xor(d, m, 64);
        }
        if (lane == 0) { AS[n * 4 + h] = s; AD[n * 4 + h] = d; }
    }
}

// ---------------------------------------------------------------------------
// CSR build: zero -> count -> 3-phase parallel scan -> fill
// ---------------------------------------------------------------------------
__global__ __launch_bounds__(256) void zero_deg_k(int* __restrict__ deg)
{
    int i = blockIdx.x * 256 + threadIdx.x;
    if (i < NN) deg[i] = 0;
}

__global__ __launch_bounds__(256) void count_deg_k(const int* __restrict__ ei, int* __restrict__ deg)
{
    int e = blockIdx.x * 256 + threadIdx.x;
    if (e >= ETOT) return;
    int dst = (e < EE) ? ei[EE + e] : e - EE;
    atomicAdd(deg + dst, 1);
}

#define NB ((NN + 255) / 256)   // 196 scan blocks

// phase A: per-block sum of 256 degrees
__global__ __launch_bounds__(256) void bsum_k(const int* __restrict__ deg, int* __restrict__ bsum)
{
    __shared__ int red[4];
    int i = blockIdx.x * 256 + threadIdx.x;
    int v = (i < NN) ? deg[i] : 0;
    #pragma unroll
    for (int m = 32; m >= 1; m >>= 1) v += __shfl_xor(v, m, 64);
    if ((threadIdx.x & 63) == 0) red[threadIdx.x >> 6] = v;
    __syncthreads();
    if (threadIdx.x == 0) bsum[blockIdx.x] = red[0] + red[1] + red[2] + red[3];
}

// phase B: exclusive scan of NB block sums (NB <= 256), one block
__global__ __launch_bounds__(256) void bscan_k(int* __restrict__ bsum)
{
    __shared__ int tmp[256];
    int t = threadIdx.x;
    int v = (t < NB) ? bsum[t] : 0;
    tmp[t] = v;
    __syncthreads();
    #pragma unroll
    for (int off = 1; off < 256; off <<= 1) {
        int u = (t >= off) ? tmp[t - off] : 0;
        __syncthreads();
        tmp[t] += u;
        __syncthreads();
    }
    if (t < NB) bsum[t] = tmp[t] - v;   // exclusive prefix
}

// phase C: per-block exclusive scan + block base -> rowptr, cursor
__global__ __launch_bounds__(256) void rowptr_k(
    const int* __restrict__ deg, const int* __restrict__ bsum,
    int* __restrict__ rowptr, int* __restrict__ cursor)
{
    __shared__ int tmp[256];
    int t = threadIdx.x;
    int i = blockIdx.x * 256 + t;
    int v = (i < NN) ? deg[i] : 0;
    tmp[t] = v;
    __syncthreads();
    #pragma unroll
    for (int off = 1; off < 256; off <<= 1) {
        int u = (t >= off) ? tmp[t - off] : 0;
        __syncthreads();
        tmp[t] += u;
        __syncthreads();
    }
    int excl = tmp[t] - v + bsum[blockIdx.x];
    if (i < NN) { rowptr[i] = excl; cursor[i] = excl; }
    if (blockIdx.x == 0 && t == 0) rowptr[NN] = ETOT;
}

__global__ __launch_bounds__(256) void fill_k(
    const int* __restrict__ ei, int* __restrict__ cursor,
    int* __restrict__ EDG, int* __restrict__ DSTOF)
{
    int e = blockIdx.x * 256 + threadIdx.x;
    if (e >= ETOT) return;
    int src, dst;
    if (e < EE) { src = ei[e]; dst = ei[EE + e]; }
    else        { src = dst = e - EE; }
    int pos = atomicAdd(cursor + dst, 1);
    EDG[pos] = src;
    DSTOF[pos] = dst;
}

// ---------------------------------------------------------------------------
// Per-edge logits in CSR order, interleaved float4 (one per edge, 4 heads).
// ---------------------------------------------------------------------------
__global__ __launch_bounds__(256) void elog_k(
    const int* __restrict__ EDG, const int* __restrict__ DSTOF,
    const float* __restrict__ AS, const float* __restrict__ AD,
    float4* __restrict__ LOG4)
{
    int e = blockIdx.x * 256 + threadIdx.x;
    if (e >= ETOT) return;
    int src = EDG[e], dst = DSTOF[e];
    float4 s4 = *reinterpret_cast<const float4*>(AS + (size_t)src * 4);
    float4 d4 = *reinterpret_cast<const float4*>(AD + (size_t)dst * 4);
    LOG4[e] = make_float4(lrelu(s4.x + d4.x), lrelu(s4.y + d4.y),
                          lrelu(s4.z + d4.z), lrelu(s4.w + d4.w));
}

// ---------------------------------------------------------------------------
// Gather-aggregate. One wave per node (4/block). Lane l: feats l*4..l*4+3,
// head = l>>4. Chunked over edges (chunk = 64).
// ---------------------------------------------------------------------------
template<int MODE>
__global__ __launch_bounds__(256) void gather_k(
    const int* __restrict__ rowptr, const int* __restrict__ EDG,
    const float4* __restrict__ LOG4, const unsigned short* __restrict__ H,
    const float* __restrict__ bias, unsigned short* __restrict__ OUT,
    float* __restrict__ OUTF)
{
    __shared__ float wT[4][4][65];   // [wave][head][edge-in-chunk], pad->4 banks
    int wid  = threadIdx.x >> 6;
    int lane = threadIdx.x & 63;
    int n = blockIdx.x * 4 + wid;
    if (n >= NN) return;
    int head = lane >> 4;

    int beg = rowptr[n], end = rowptr[n + 1];

    // ---- pass 1: per-head max over edges ----
    float4 m4 = make_float4(NINF, NINF, NINF, NINF);
    for (int b = beg; b < end; b += 64) {
        int l = b + lane;
        if (l < end) {
            float4 lg = LOG4[l];
            m4.x = fmaxf(m4.x, lg.x); m4.y = fmaxf(m4.y, lg.y);
            m4.z = fmaxf(m4.z, lg.z); m4.w = fmaxf(m4.w, lg.w);
        }
    }
    #pragma unroll
    for (int msk = 1; msk <= 32; msk <<= 1) {
        m4.x = fmaxf(m4.x, __shfl_xor(m4.x, msk, 64));
        m4.y = fmaxf(m4.y, __shfl_xor(m4.y, msk, 64));
        m4.z = fmaxf(m4.z, __shfl_xor(m4.z, msk, 64));
        m4.w = fmaxf(m4.w, __shfl_xor(m4.w, msk, 64));
    }

    // ---- pass 2: weights + weighted feature accumulation ----
    float4 den4 = make_float4(0.f, 0.f, 0.f, 0.f);
    float a0 = 0.f, a1 = 0.f, a2 = 0.f, a3 = 0.f;
    const unsigned short* hp = H + lane * 4;

    for (int b = beg; b < end; b += 64) {
        int cd = min(end - b, 64);
        int srcv = (lane < cd) ? EDG[b + lane] : 0;
        float4 w4 = make_float4(0.f, 0.f, 0.f, 0.f);
        if (lane < cd) {
            float4 lg = LOG4[b + lane];
            w4.x = __expf(lg.x - m4.x); w4.y = __expf(lg.y - m4.y);
            w4.z = __expf(lg.z - m4.z); w4.w = __expf(lg.w - m4.w);
        }
        den4.x += w4.x; den4.y += w4.y; den4.z += w4.z; den4.w += w4.w;
        wT[wid][0][lane] = w4.x;
        wT[wid][1][lane] = w4.y;
        wT[wid][2][lane] = w4.z;
        wT[wid][3][lane] = w4.w;
        for (int j = 0; j < cd; j++) {
            int   src = __builtin_amdgcn_readlane(srcv, j);
            float wj  = wT[wid][head][j];
            ushort4 hv = *reinterpret_cast<const ushort4*>(hp + (size_t)src * 256);
            a0 += wj * b2f(hv.x); a1 += wj * b2f(hv.y);
            a2 += wj * b2f(hv.z); a3 += wj * b2f(hv.w);
        }
    }

    #pragma unroll
    for (int msk = 1; msk <= 32; msk <<= 1) {
        den4.x += __shfl_xor(den4.x, msk, 64);
        den4.y += __shfl_xor(den4.y, msk, 64);
        den4.z += __shfl_xor(den4.z, msk, 64);
        den4.w += __shfl_xor(den4.w, msk, 64);
    }
    float den = head == 0 ? den4.x : head == 1 ? den4.y : head == 2 ? den4.z : den4.w;
    float inv = 1.f / den;   // self-loop guarantees den > 0

    if (MODE == 1) {
        float4 bv = *reinterpret_cast<const float4*>(bias + lane * 4);
        ushort4 o;
        o.x = f2b(fmaxf(a0 * inv + bv.x, 0.f));
        o.y = f2b(fmaxf(a1 * inv + bv.y, 0.f));
        o.z = f2b(fmaxf(a2 * inv + bv.z, 0.f));
        o.w = f2b(fmaxf(a3 * inv + bv.w, 0.f));
        *reinterpret_cast<ushort4*>(OUT + (size_t)n * 256 + lane * 4) = o;
    } else {
        float v0 = a0 * inv, v1 = a1 * inv, v2 = a2 * inv, v3 = a3 * inv;
        #pragma unroll
        for (int msk = 16; msk <= 32; msk <<= 1) {
            v0 += __shfl_xor(v0, msk, 64);
            v1 += __shfl_xor(v1, msk, 64);
            v2 += __shfl_xor(v2, msk, 64);
            v3 += __shfl_xor(v3, msk, 64);
        }
        if (lane < 16) {
            float4* o = reinterpret_cast<float4*>(OUTF + (size_t)n * 64 + lane * 4);
            float4 cur = *o;
            cur.x += 0.25f * v0;
            cur.y += 0.25f * v1;
            cur.z += 0.25f * v2;
            cur.w += 0.25f * v3;
            *o = cur;
        }
    }
}

// ---------------------------------------------------------------------------
// fp32 vector GEMM for the root skip (64 cols): OUT = root@Wr.T + br + b2.
// ---------------------------------------------------------------------------
#define BM 64
#define BN 64
#define BKT 64

__global__ __launch_bounds__(256) void gemm_tn(
    const float* __restrict__ A, const float* __restrict__ W,
    float* __restrict__ C, int Mrows, int ncols,
    const float* __restrict__ bias0, const float* __restrict__ bias1)
{
    __shared__ float As[BKT][BM + 4];
    __shared__ float Bs[BKT][BN + 4];

    const int tid = threadIdx.x;
    const int rg = tid >> 4;
    const int cg = tid & 15;
    const int n0 = blockIdx.x * BM;
    const int c0 = blockIdx.y * BN;

    float acc[4][4];
    #pragma unroll
    for (int i = 0; i < 4; i++)
        #pragma unroll
        for (int j = 0; j < 4; j++) acc[i][j] = 0.f;

    for (int k0 = 0; k0 < KDIM; k0 += BKT) {
        #pragma unroll
        for (int i = 0; i < 4; i++) {
            int f  = tid + 256 * i;
            int r  = f >> 4;
            int kq = f & 15;
            float4 v = make_float4(0.f, 0.f, 0.f, 0.f);
            int gr = n0 + r;
            if (gr < Mrows)
                v = *reinterpret_cast<const float4*>(A + (size_t)gr * KDIM + k0 + kq * 4);
            As[kq * 4 + 0][r] = v.x;
            As[kq * 4 + 1][r] = v.y;
            As[kq * 4 + 2][r] = v.z;
            As[kq * 4 + 3][r] = v.w;
        }
        #pragma unroll
        for (int i = 0; i < 4; i++) {
            int f  = tid + 256 * i;
            int c  = f >> 4;
            int kq = f & 15;
            float4 v = *reinterpret_cast<const float4*>(W + (size_t)(c0 + c) * KDIM + k0 + kq * 4);
            Bs[kq * 4 + 0][c] = v.x;
            Bs[kq * 4 + 1][c] = v.y;
            Bs[kq * 4 + 2][c] = v.z;
            Bs[kq * 4 + 3][c] = v.w;
        }
        __syncthreads();

        #pragma unroll 16
        for (int k = 0; k < BKT; k++) {
            float4 a = *reinterpret_cast<const float4*>(&As[k][rg * 4]);
            float4 b = *reinterpret_cast<const float4*>(&Bs[k][cg * 4]);
            acc[0][0] += a.x * b.x; acc[0][1] += a.x * b.y; acc[0][2] += a.x * b.z; acc[0][3] += a.x * b.w;
            acc[1][0] += a.y * b.x; acc[1][1] += a.y * b.y; acc[1][2] += a.y * b.z; acc[1][3] += a.y * b.w;
            acc[2][0] += a.z * b.x; acc[2][1] += a.z * b.y; acc[2][2] += a.z * b.z; acc[2][3] += a.z * b.w;
            acc[3][0] += a.w * b.x; acc[3][1] += a.w * b.y; acc[3][2] += a.w * b.z; acc[3][3] += a.w * b.w;
        }
        __syncthreads();
    }

    #pragma unroll
    for (int i = 0; i < 4; i++) {
        int gr = n0 + rg * 4 + i;
        if (gr >= Mrows) continue;
        float4 v = make_float4(acc[i][0], acc[i][1], acc[i][2], acc[i][3]);
        int gc = c0 + cg * 4;
        if (bias0) { v.x += bias0[gc + 0]; v.y += bias0[gc + 1]; v.z += bias0[gc + 2]; v.w += bias0[gc + 3]; }
        if (bias1) { v.x += bias1[gc + 0]; v.y += bias1[gc + 1]; v.z += bias1[gc + 2]; v.w += bias1[gc + 3]; }
        *reinterpret_cast<float4*>(C + (size_t)gr * ncols + gc) = v;
    }
}

// ---------------------------------------------------------------------------
extern "C" void kernel_launch(void* const* d_in, const int* in_sizes, int n_in,
                              void* d_out, int out_size, void* d_ws, size_t ws_size,
                              hipStream_t stream) {
    const float* x    = (const float*)d_in[0];
    const float* root = (const float*)d_in[1];
    const int*   ei   = (const int*)  d_in[2];
    const float* W1   = (const float*)d_in[3];
    const float* as1  = (const float*)d_in[4];
    const float* ad1  = (const float*)d_in[5];
    const float* b1   = (const float*)d_in[6];
    const float* W2   = (const float*)d_in[7];
    const float* as2  = (const float*)d_in[8];
    const float* ad2  = (const float*)d_in[9];
    const float* b2   = (const float*)d_in[10];
    const float* Wr   = (const float*)d_in[11];
    const float* br   = (const float*)d_in[12];
    float* out = (float*)d_out;

    unsigned short* xb  = (unsigned short*)d_ws;             // N*256
    unsigned short* Hb  = xb  + (size_t)NN * 256;            // N*256
    unsigned short* X2b = Hb  + (size_t)NN * 256;            // N*256
    unsigned short* w1b = X2b + (size_t)NN * 256;            // 65536
    unsigned short* w2b = w1b + 65536;                       // 65536
    float* AS  = (float*)(w2b + 65536);                      // N*4
    float* AD  = AS + (size_t)NN * 4;                        // N*4
    float4* LOG4 = (float4*)(AD + (size_t)NN * 4);           // ETOT float4
    int*   deg    = (int*)(LOG4 + (size_t)ETOT);             // N
    int*   rowptr = deg + NN;                                // N+1
    int*   cursor = rowptr + NN + 1;                         // N
    int*   bsum   = cursor + NN;                             // NB
    int*   EDG    = bsum + 256;                              // ETOT
    int*   DSTOF  = EDG + ETOT;                              // ETOT

    const int egrid = (ETOT + 255) / 256;
    const int ngrid = (NN + 255) / 256;
    const int wgrid = (NN + 3) / 4;
    const int mgrid = (NN + 63) / 64;

    // ----- CSR build -----
    zero_deg_k<<<ngrid, 256, 0, stream>>>(deg);
    count_deg_k<<<egrid, 256, 0, stream>>>(ei, deg);
    bsum_k<<<NB, 256, 0, stream>>>(deg, bsum);
    bscan_k<<<1, 256, 0, stream>>>(bsum);
    rowptr_k<<<NB, 256, 0, stream>>>(deg, bsum, rowptr, cursor);
    fill_k<<<egrid, 256, 0, stream>>>(ei, cursor, EDG, DSTOF);

    // ----- casts -----
    cast_k<<<(NN * 256 / 4 + 255) / 256, 256, 0, stream>>>(x, xb, NN * 256);
    cast_k<<<(65536 / 4 + 255) / 256, 256, 0, stream>>>(W1, w1b, 65536);
    cast_k<<<(65536 / 4 + 255) / 256, 256, 0, stream>>>(W2, w2b, 65536);

    // ----- layer 1 -----
    gemm_mfma<<<mgrid, 256, 0, stream>>>(xb, w1b, Hb, NN);
    alphas_k<<<wgrid, 256, 0, stream>>>(Hb, as1, ad1, AS, AD);
    elog_k<<<egrid, 256, 0, stream>>>(EDG, DSTOF, AS, AD, LOG4);
    gather_k<1><<<wgrid, 256, 0, stream>>>(rowptr, EDG, LOG4, Hb, b1, X2b, nullptr);

    // ----- layer 2 -----
    gemm_mfma<<<mgrid, 256, 0, stream>>>(X2b, w2b, Hb, NN);
    alphas_k<<<wgrid, 256, 0, stream>>>(Hb, as2, ad2, AS, AD);
    elog_k<<<egrid, 256, 0, stream>>>(EDG, DSTOF, AS, AD, LOG4);

    // root skip + biases into d_out (fp32), then gather adds head-mean
    gemm_tn<<<dim3((NN + BM - 1) / BM, 1), 256, 0, stream>>>(root, Wr, out, NN, 64, br, b2);
    gather_k<2><<<wgrid, 256, 0, stream>>>(rowptr, EDG, LOG4, Hb, nullptr, nullptr, out);
}

// Round 7
// 426.348 us; speedup vs baseline: 2.0684x; 1.2105x over previous
//
#include <hip/hip_runtime.h>
#include <hip/hip_bf16.h>
#include <math.h>

#define NN   50000
#define EE   800000
#define ETOT (EE + NN)
#define KDIM 256
#define HEADS 4
#define HIDD 64

typedef float  f32x4  __attribute__((ext_vector_type(4)));
typedef short  bf16x8 __attribute__((ext_vector_type(8)));

__device__ __forceinline__ float b2f(unsigned short u) {
    union { float f; unsigned int i; } v; v.i = (unsigned int)u << 16; return v.f;
}
__device__ __forceinline__ unsigned short f2b(float f) {
    union { float f; unsigned int i; } v; v.f = f;
    return (unsigned short)((v.i + 0x7fffu + ((v.i >> 16) & 1u)) >> 16);
}
__device__ __forceinline__ float lrelu(float x) { return x >= 0.f ? x : 0.2f * x; }

// ---------------------------------------------------------------------------
// fp32 -> bf16 cast (weights only now). n multiple of 4.
// ---------------------------------------------------------------------------
__global__ __launch_bounds__(256) void cast_k(
    const float* __restrict__ in, unsigned short* __restrict__ out, int n)
{
    int i = (blockIdx.x * 256 + threadIdx.x) * 4;
    if (i >= n) return;
    float4 v = *reinterpret_cast<const float4*>(in + i);
    ushort4 o;
    o.x = f2b(v.x); o.y = f2b(v.y); o.z = f2b(v.z); o.w = f2b(v.w);
    *reinterpret_cast<ushort4*>(out + i) = o;
}

// ---------------------------------------------------------------------------
// Fused MFMA GEMM (TN): C[m][c] = sum_k A[m][k]*W[c][k], K=256.
// AF32: A is fp32, converted to bf16 in-register. NCT: #16-col tiles (16 or 4).
// ALPHA: epilogue computes AS[n][h]=dot(row, a_src[h]), AD likewise, from the
//        accumulator (row n's 256 cols live in the 16 lanes sharing kg).
// OUTF32: write fp32 + bias0 + bias1 (root path); else bf16.
// One wave per 16-row tile; 4 waves/block.
// ---------------------------------------------------------------------------
template<bool AF32, int NCT, bool ALPHA, bool OUTF32>
__global__ __launch_bounds__(256) void gemm_mfma(
    const void* __restrict__ Ain, const unsigned short* __restrict__ W,
    void* __restrict__ Cout, int Mrows,
    const float* __restrict__ av_src, const float* __restrict__ av_dst,
    float* __restrict__ AS, float* __restrict__ AD,
    const float* __restrict__ bias0, const float* __restrict__ bias1)
{
    int wid  = threadIdx.x >> 6;
    int lane = threadIdx.x & 63;
    int m0 = (blockIdx.x * 4 + wid) * 16;
    if (m0 >= Mrows) return;
    int cl = lane & 15;
    int kg = lane >> 4;

    int arow = m0 + cl; if (arow >= Mrows) arow = Mrows - 1;

    f32x4 acc[NCT];
    #pragma unroll
    for (int ct = 0; ct < NCT; ct++) acc[ct] = (f32x4)(0.f);

    for (int k0 = 0; k0 < KDIM; k0 += 32) {
        bf16x8 a;
        if constexpr (AF32) {
            const float* A = (const float*)Ain;
            const float* ap = A + (size_t)arow * KDIM + k0 + kg * 8;
            float4 v0 = *reinterpret_cast<const float4*>(ap);
            float4 v1 = *reinterpret_cast<const float4*>(ap + 4);
            a[0] = (short)f2b(v0.x); a[1] = (short)f2b(v0.y);
            a[2] = (short)f2b(v0.z); a[3] = (short)f2b(v0.w);
            a[4] = (short)f2b(v1.x); a[5] = (short)f2b(v1.y);
            a[6] = (short)f2b(v1.z); a[7] = (short)f2b(v1.w);
        } else {
            const unsigned short* A = (const unsigned short*)Ain;
            a = *reinterpret_cast<const bf16x8*>(A + (size_t)arow * KDIM + k0 + kg * 8);
        }
        #pragma unroll
        for (int ct = 0; ct < NCT; ct++) {
            bf16x8 b = *reinterpret_cast<const bf16x8*>(
                W + (size_t)(ct * 16 + cl) * KDIM + k0 + kg * 8);
            acc[ct] = __builtin_amdgcn_mfma_f32_16x16x32_bf16(a, b, acc[ct], 0, 0, 0);
        }
    }

    // ---- C write ----
    if constexpr (OUTF32) {
        float* C = (float*)Cout;
        #pragma unroll
        for (int ct = 0; ct < NCT; ct++) {
            #pragma unroll
            for (int r = 0; r < 4; r++) {
                int n = m0 + kg * 4 + r;
                int c = ct * 16 + cl;
                if (n < Mrows)
                    C[(size_t)n * (NCT * 16) + c] = acc[ct][r] + bias0[c] + bias1[c];
            }
        }
    } else {
        unsigned short* C = (unsigned short*)Cout;
        #pragma unroll
        for (int ct = 0; ct < NCT; ct++) {
            #pragma unroll
            for (int r = 0; r < 4; r++) {
                int n = m0 + kg * 4 + r;
                if (n < Mrows)
                    C[(size_t)n * (NCT * 16) + ct * 16 + cl] = f2b(acc[ct][r]);
            }
        }
    }

    // ---- fused attention-term epilogue ----
    if constexpr (ALPHA) {
        float asr[NCT], adr[NCT];
        #pragma unroll
        for (int ct = 0; ct < NCT; ct++) {
            int c = ct * 16 + cl;
            asr[ct] = av_src[c];
            adr[ct] = av_dst[c];
        }
        #pragma unroll
        for (int r = 0; r < 4; r++) {
            int n = m0 + kg * 4 + r;
            f32x4 s4 = (f32x4)(0.f), d4 = (f32x4)(0.f);
            #pragma unroll
            for (int h = 0; h < 4; h++) {
                #pragma unroll
                for (int q = 0; q < 4; q++) {
                    s4[h] += acc[h * 4 + q][r] * asr[h * 4 + q];
                    d4[h] += acc[h * 4 + q][r] * adr[h * 4 + q];
                }
            }
            #pragma unroll
            for (int msk = 1; msk <= 8; msk <<= 1) {
                #pragma unroll
                for (int h = 0; h < 4; h++) {
                    s4[h] += __shfl_xor(s4[h], msk, 64);
                    d4[h] += __shfl_xor(d4[h], msk, 64);
                }
            }
            if (cl == 0 && n < Mrows) {
                *reinterpret_cast<float4*>(AS + (size_t)n * 4) =
                    make_float4(s4[0], s4[1], s4[2], s4[3]);
                *reinterpret_cast<float4*>(AD + (size_t)n * 4) =
                    make_float4(d4[0], d4[1], d4[2], d4[3]);
            }
        }
    }
}

// ---------------------------------------------------------------------------
// CSR build: zero -> count -> 3-phase parallel scan -> fill
// ---------------------------------------------------------------------------
__global__ __launch_bounds__(256) void zero_deg_k(int* __restrict__ deg)
{
    int i = blockIdx.x * 256 + threadIdx.x;
    if (i < NN) deg[i] = 0;
}

__global__ __launch_bounds__(256) void count_deg_k(const int* __restrict__ ei, int* __restrict__ deg)
{
    int e = blockIdx.x * 256 + threadIdx.x;
    if (e >= ETOT) return;
    int dst = (e < EE) ? ei[EE + e] : e - EE;
    atomicAdd(deg + dst, 1);
}

#define NB ((NN + 255) / 256)   // 196 scan blocks

__global__ __launch_bounds__(256) void bsum_k(const int* __restrict__ deg, int* __restrict__ bsum)
{
    __shared__ int red[4];
    int i = blockIdx.x * 256 + threadIdx.x;
    int v = (i < NN) ? deg[i] : 0;
    #pragma unroll
    for (int m = 32; m >= 1; m >>= 1) v += __shfl_xor(v, m, 64);
    if ((threadIdx.x & 63) == 0) red[threadIdx.x >> 6] = v;
    __syncthreads();
    if (threadIdx.x == 0) bsum[blockIdx.x] = red[0] + red[1] + red[2] + red[3];
}

__global__ __launch_bounds__(256) void bscan_k(int* __restrict__ bsum)
{
    __shared__ int tmp[256];
    int t = threadIdx.x;
    int v = (t < NB) ? bsum[t] : 0;
    tmp[t] = v;
    __syncthreads();
    #pragma unroll
    for (int off = 1; off < 256; off <<= 1) {
        int u = (t >= off) ? tmp[t - off] : 0;
        __syncthreads();
        tmp[t] += u;
        __syncthreads();
    }
    if (t < NB) bsum[t] = tmp[t] - v;   // exclusive prefix
}

__global__ __launch_bounds__(256) void rowptr_k(
    const int* __restrict__ deg, const int* __restrict__ bsum,
    int* __restrict__ rowptr, int* __restrict__ cursor)
{
    __shared__ int tmp[256];
    int t = threadIdx.x;
    int i = blockIdx.x * 256 + t;
    int v = (i < NN) ? deg[i] : 0;
    tmp[t] = v;
    __syncthreads();
    #pragma unroll
    for (int off = 1; off < 256; off <<= 1) {
        int u = (t >= off) ? tmp[t - off] : 0;
        __syncthreads();
        tmp[t] += u;
        __syncthreads();
    }
    int excl = tmp[t] - v + bsum[blockIdx.x];
    if (i < NN) { rowptr[i] = excl; cursor[i] = excl; }
    if (blockIdx.x == 0 && t == 0) rowptr[NN] = ETOT;
}

__global__ __launch_bounds__(256) void fill_k(
    const int* __restrict__ ei, int* __restrict__ cursor, int* __restrict__ EDG)
{
    int e = blockIdx.x * 256 + threadIdx.x;
    if (e >= ETOT) return;
    int src, dst;
    if (e < EE) { src = ei[e]; dst = ei[EE + e]; }
    else        { src = dst = e - EE; }
    int pos = atomicAdd(cursor + dst, 1);
    EDG[pos] = src;
}

// ---------------------------------------------------------------------------
// Single-pass gather-aggregate (no max shift: softmax is shift-invariant and
// logits are bounded |logit| < ~25 -> exp stays in fp32 range).
// One wave per node (4/block). Lane l: feats l*4..l*4+3, head = l>>4.
// Per 64-edge chunk: lane owns edge (srcv, AS[srcv] random 16B from L2),
// computes 4-head weights, stashes them in a padded LDS table; inner j-loop
// broadcasts src via readlane (scalar-addressed H loads, all independent).
// MODE 1: OUT(bf16)[n][c] = relu(acc/den + bias).
// MODE 2: OUTF(f32)[n][c64] += 0.25 * sum_h acc_h/den_h (root skip already in OUTF).
// ---------------------------------------------------------------------------
template<int MODE>
__global__ __launch_bounds__(256) void gather_k(
    const int* __restrict__ rowptr, const int* __restrict__ EDG,
    const float* __restrict__ AS, const float* __restrict__ AD,
    const unsigned short* __restrict__ H, const float* __restrict__ bias,
    unsigned short* __restrict__ OUT, float* __restrict__ OUTF)
{
    __shared__ float wT[4][4][65];   // [wave][head][edge-in-chunk], pad->distinct banks
    int wid  = threadIdx.x >> 6;
    int lane = threadIdx.x & 63;
    int n = blockIdx.x * 4 + wid;
    if (n >= NN) return;
    int head = lane >> 4;

    int beg = rowptr[n], end = rowptr[n + 1];
    float4 ad4 = *reinterpret_cast<const float4*>(AD + (size_t)n * 4);

    float4 den4 = make_float4(0.f, 0.f, 0.f, 0.f);
    float a0 = 0.f, a1 = 0.f, a2 = 0.f, a3 = 0.f;
    const unsigned short* hp = H + lane * 4;

    for (int b = beg; b < end; b += 64) {
        int cd = min(end - b, 64);
        int srcv = (lane < cd) ? EDG[b + lane] : 0;
        float4 w4 = make_float4(0.f, 0.f, 0.f, 0.f);
        if (lane < cd) {
            float4 s4 = *reinterpret_cast<const float4*>(AS + (size_t)srcv * 4);
            w4.x = __expf(lrelu(s4.x + ad4.x));
            w4.y = __expf(lrelu(s4.y + ad4.y));
            w4.z = __expf(lrelu(s4.z + ad4.z));
            w4.w = __expf(lrelu(s4.w + ad4.w));
        }
        den4.x += w4.x; den4.y += w4.y; den4.z += w4.z; den4.w += w4.w;
        wT[wid][0][lane] = w4.x;
        wT[wid][1][lane] = w4.y;
        wT[wid][2][lane] = w4.z;
        wT[wid][3][lane] = w4.w;
        for (int j = 0; j < cd; j++) {
            int   src = __builtin_amdgcn_readlane(srcv, j);
            float wj  = wT[wid][head][j];
            ushort4 hv = *reinterpret_cast<const ushort4*>(hp + (size_t)src * 256);
            a0 += wj * b2f(hv.x); a1 += wj * b2f(hv.y);
            a2 += wj * b2f(hv.z); a3 += wj * b2f(hv.w);
        }
    }

    #pragma unroll
    for (int msk = 1; msk <= 32; msk <<= 1) {
        den4.x += __shfl_xor(den4.x, msk, 64);
        den4.y += __shfl_xor(den4.y, msk, 64);
        den4.z += __shfl_xor(den4.z, msk, 64);
        den4.w += __shfl_xor(den4.w, msk, 64);
    }
    float den = head == 0 ? den4.x : head == 1 ? den4.y : head == 2 ? den4.z : den4.w;
    float inv = 1.f / den;   // self-loop guarantees den > 0

    if (MODE == 1) {
        float4 bv = *reinterpret_cast<const float4*>(bias + lane * 4);
        ushort4 o;
        o.x = f2b(fmaxf(a0 * inv + bv.x, 0.f));
        o.y = f2b(fmaxf(a1 * inv + bv.y, 0.f));
        o.z = f2b(fmaxf(a2 * inv + bv.z, 0.f));
        o.w = f2b(fmaxf(a3 * inv + bv.w, 0.f));
        *reinterpret_cast<ushort4*>(OUT + (size_t)n * 256 + lane * 4) = o;
    } else {
        float v0 = a0 * inv, v1 = a1 * inv, v2 = a2 * inv, v3 = a3 * inv;
        #pragma unroll
        for (int msk = 16; msk <= 32; msk <<= 1) {
            v0 += __shfl_xor(v0, msk, 64);
            v1 += __shfl_xor(v1, msk, 64);
            v2 += __shfl_xor(v2, msk, 64);
            v3 += __shfl_xor(v3, msk, 64);
        }
        if (lane < 16) {
            float4* o = reinterpret_cast<float4*>(OUTF + (size_t)n * 64 + lane * 4);
            float4 cur = *o;
            cur.x += 0.25f * v0;
            cur.y += 0.25f * v1;
            cur.z += 0.25f * v2;
            cur.w += 0.25f * v3;
            *o = cur;
        }
    }
}

// ---------------------------------------------------------------------------
extern "C" void kernel_launch(void* const* d_in, const int* in_sizes, int n_in,
                              void* d_out, int out_size, void* d_ws, size_t ws_size,
                              hipStream_t stream) {
    const float* x    = (const float*)d_in[0];
    const float* root = (const float*)d_in[1];
    const int*   ei   = (const int*)  d_in[2];
    const float* W1   = (const float*)d_in[3];
    const float* as1  = (const float*)d_in[4];
    const float* ad1  = (const float*)d_in[5];
    const float* b1   = (const float*)d_in[6];
    const float* W2   = (const float*)d_in[7];
    const float* as2  = (const float*)d_in[8];
    const float* ad2  = (const float*)d_in[9];
    const float* b2   = (const float*)d_in[10];
    const float* Wr   = (const float*)d_in[11];
    const float* br   = (const float*)d_in[12];
    float* out = (float*)d_out;

    unsigned short* Hb  = (unsigned short*)d_ws;             // N*256
    unsigned short* X2b = Hb  + (size_t)NN * 256;            // N*256
    unsigned short* w1b = X2b + (size_t)NN * 256;            // 65536
    unsigned short* w2b = w1b + 65536;                       // 65536
    unsigned short* wrb = w2b + 65536;                       // 16384
    float* AS  = (float*)(wrb + 16384);                      // N*4
    float* AD  = AS + (size_t)NN * 4;                        // N*4
    int*   deg    = (int*)(AD + (size_t)NN * 4);             // N
    int*   rowptr = deg + NN;                                // N+1
    int*   cursor = rowptr + NN + 1;                         // N
    int*   bsum   = cursor + NN;                             // 256
    int*   EDG    = bsum + 256;                              // ETOT

    const int egrid = (ETOT + 255) / 256;
    const int ngrid = (NN + 255) / 256;
    const int wgrid = (NN + 3) / 4;
    const int mgrid = (NN + 63) / 64;

    // ----- CSR build -----
    zero_deg_k<<<ngrid, 256, 0, stream>>>(deg);
    count_deg_k<<<egrid, 256, 0, stream>>>(ei, deg);
    bsum_k<<<NB, 256, 0, stream>>>(deg, bsum);
    bscan_k<<<1, 256, 0, stream>>>(bsum);
    rowptr_k<<<NB, 256, 0, stream>>>(deg, bsum, rowptr, cursor);
    fill_k<<<egrid, 256, 0, stream>>>(ei, cursor, EDG);

    // ----- weight casts -----
    cast_k<<<(65536 / 4 + 255) / 256, 256, 0, stream>>>(W1, w1b, 65536);
    cast_k<<<(65536 / 4 + 255) / 256, 256, 0, stream>>>(W2, w2b, 65536);
    cast_k<<<(16384 / 4 + 255) / 256, 256, 0, stream>>>(Wr, wrb, 16384);

    // ----- layer 1: fp32 x -> bf16 H + fused AS/AD -----
    gemm_mfma<true, 16, true, false><<<mgrid, 256, 0, stream>>>(
        x, w1b, Hb, NN, as1, ad1, AS, AD, nullptr, nullptr);
    gather_k<1><<<wgrid, 256, 0, stream>>>(rowptr, EDG, AS, AD, Hb, b1, X2b, nullptr);

    // ----- layer 2: bf16 X2 -> bf16 H + fused AS/AD -----
    gemm_mfma<false, 16, true, false><<<mgrid, 256, 0, stream>>>(
        X2b, w2b, Hb, NN, as2, ad2, AS, AD, nullptr, nullptr);

    // ----- root skip (fp32 root -> fp32 out + br + b2), then head-mean add -----
    gemm_mfma<true, 4, false, true><<<mgrid, 256, 0, stream>>>(
        root, wrb, out, NN, nullptr, nullptr, nullptr, nullptr, br, b2);
    gather_k<2><<<wgrid, 256, 0, stream>>>(rowptr, EDG, AS, AD, Hb, nullptr, nullptr, out);
}

// Round 8
// 326.958 us; speedup vs baseline: 2.6971x; 1.3040x over previous
//
#include <hip/hip_runtime.h>
#include <hip/hip_bf16.h>
#include <math.h>

#define NN   50000
#define EE   800000
#define ETOT (EE + NN)
#define KDIM 256
#define HEADS 4
#define HIDD 64

typedef float  f32x4  __attribute__((ext_vector_type(4)));
typedef short  bf16x8 __attribute__((ext_vector_type(8)));

__device__ __forceinline__ float b2f(unsigned short u) {
    union { float f; unsigned int i; } v; v.i = (unsigned int)u << 16; return v.f;
}
__device__ __forceinline__ unsigned short f2b(float f) {
    union { float f; unsigned int i; } v; v.f = f;
    return (unsigned short)((v.i + 0x7fffu + ((v.i >> 16) & 1u)) >> 16);
}
__device__ __forceinline__ float lrelu(float x) { return x >= 0.f ? x : 0.2f * x; }

// ---------------------------------------------------------------------------
// fp32 -> bf16 cast (weights only). n multiple of 4.
// ---------------------------------------------------------------------------
__global__ __launch_bounds__(256) void cast_k(
    const float* __restrict__ in, unsigned short* __restrict__ out, int n)
{
    int i = (blockIdx.x * 256 + threadIdx.x) * 4;
    if (i >= n) return;
    float4 v = *reinterpret_cast<const float4*>(in + i);
    ushort4 o;
    o.x = f2b(v.x); o.y = f2b(v.y); o.z = f2b(v.z); o.w = f2b(v.w);
    *reinterpret_cast<ushort4*>(out + i) = o;
}

// ---------------------------------------------------------------------------
// Fused MFMA GEMM (TN), LDS-staged W, double-buffered K-slices of 32.
// C[m][c] = sum_k A[m][k]*W[c][k], K=256. Block: 4 waves x 16 rows = 64 rows.
// W slice [ROWS][32] staged to LDS padded [ROWS][40] (row stride 80 B -> 8
// distinct banks for the 16 cl lanes, 2-way conflict = free).
// AF32: A fp32, in-register bf16 convert. NCT: 16-col tiles (16 or 4).
// ALPHA: epilogue computes AS/AD = dot(row, a_src/a_dst) from the accumulator.
// OUTF32: fp32 C + bias0 + bias1 (root path); else bf16 C.
// NOTE: no early return — all threads participate in barriers; writes guarded.
// ---------------------------------------------------------------------------
template<bool AF32, int NCT, bool ALPHA, bool OUTF32>
__global__ __launch_bounds__(256) void gemm_mfma(
    const void* __restrict__ Ain, const unsigned short* __restrict__ W,
    void* __restrict__ Cout, int Mrows,
    const float* __restrict__ av_src, const float* __restrict__ av_dst,
    float* __restrict__ AS, float* __restrict__ AD,
    const float* __restrict__ bias0, const float* __restrict__ bias1)
{
    constexpr int ROWS = NCT * 16;            // 256 or 64
    constexpr int KS   = 32;                  // k-slice
    constexpr int LDK  = 40;                  // padded row (ushorts)
    constexpr int NSL  = KDIM / KS;           // 8 slices
    constexpr int NLD  = (ROWS * KS) / (256 * 8);   // ushort8 chunks/thread (4 or 1)
    __shared__ unsigned short Wl[2][ROWS][LDK];

    const int t    = threadIdx.x;
    const int wid  = t >> 6;
    const int lane = t & 63;
    const int cl   = lane & 15;
    const int kg   = lane >> 4;
    const int m0   = (blockIdx.x * 4 + wid) * 16;

    int arow = m0 + cl; if (arow >= Mrows) arow = Mrows - 1;

    bf16x8 stg[NLD];
    auto LOADSTG = [&](int s) {
        #pragma unroll
        for (int i = 0; i < NLD; i++) {
            int f = i * 256 + t;
            int c = f >> 2, kc = f & 3;     // 4 ushort8-chunks per 32-k row
            stg[i] = *reinterpret_cast<const bf16x8*>(
                W + (size_t)c * KDIM + s * KS + kc * 8);
        }
    };
    auto WRITESTG = [&](int b) {
        #pragma unroll
        for (int i = 0; i < NLD; i++) {
            int f = i * 256 + t;
            int c = f >> 2, kc = f & 3;
            *reinterpret_cast<bf16x8*>(&Wl[b][c][kc * 8]) = stg[i];
        }
    };
    auto LOADA = [&](int s) -> bf16x8 {
        if constexpr (AF32) {
            const float* ap = (const float*)Ain + (size_t)arow * KDIM + s * KS + kg * 8;
            float4 v0 = *reinterpret_cast<const float4*>(ap);
            float4 v1 = *reinterpret_cast<const float4*>(ap + 4);
            bf16x8 a;
            a[0] = (short)f2b(v0.x); a[1] = (short)f2b(v0.y);
            a[2] = (short)f2b(v0.z); a[3] = (short)f2b(v0.w);
            a[4] = (short)f2b(v1.x); a[5] = (short)f2b(v1.y);
            a[6] = (short)f2b(v1.z); a[7] = (short)f2b(v1.w);
            return a;
        } else {
            return *reinterpret_cast<const bf16x8*>(
                (const unsigned short*)Ain + (size_t)arow * KDIM + s * KS + kg * 8);
        }
    };

    f32x4 acc[NCT];
    #pragma unroll
    for (int ct = 0; ct < NCT; ct++) acc[ct] = (f32x4)(0.f);

    LOADSTG(0);
    WRITESTG(0);
    bf16x8 a_cur = LOADA(0);
    __syncthreads();

    int buf = 0;
    for (int s = 0; s < NSL; s++) {
        bf16x8 a_nxt;
        if (s + 1 < NSL) { LOADSTG(s + 1); a_nxt = LOADA(s + 1); }
        #pragma unroll
        for (int ct = 0; ct < NCT; ct++) {
            bf16x8 b = *reinterpret_cast<const bf16x8*>(&Wl[buf][ct * 16 + cl][kg * 8]);
            acc[ct] = __builtin_amdgcn_mfma_f32_16x16x32_bf16(a_cur, b, acc[ct], 0, 0, 0);
        }
        if (s + 1 < NSL) {
            WRITESTG(buf ^ 1);
            __syncthreads();
            buf ^= 1;
            a_cur = a_nxt;
        }
    }

    // ---- C write ----
    if constexpr (OUTF32) {
        float* C = (float*)Cout;
        #pragma unroll
        for (int ct = 0; ct < NCT; ct++) {
            #pragma unroll
            for (int r = 0; r < 4; r++) {
                int n = m0 + kg * 4 + r;
                int c = ct * 16 + cl;
                if (n < Mrows)
                    C[(size_t)n * (NCT * 16) + c] = acc[ct][r] + bias0[c] + bias1[c];
            }
        }
    } else {
        unsigned short* C = (unsigned short*)Cout;
        #pragma unroll
        for (int ct = 0; ct < NCT; ct++) {
            #pragma unroll
            for (int r = 0; r < 4; r++) {
                int n = m0 + kg * 4 + r;
                if (n < Mrows)
                    C[(size_t)n * (NCT * 16) + ct * 16 + cl] = f2b(acc[ct][r]);
            }
        }
    }

    // ---- fused attention-term epilogue ----
    if constexpr (ALPHA) {
        float asr[NCT], adr[NCT];
        #pragma unroll
        for (int ct = 0; ct < NCT; ct++) {
            int c = ct * 16 + cl;
            asr[ct] = av_src[c];
            adr[ct] = av_dst[c];
        }
        #pragma unroll
        for (int r = 0; r < 4; r++) {
            int n = m0 + kg * 4 + r;
            f32x4 s4 = (f32x4)(0.f), d4 = (f32x4)(0.f);
            #pragma unroll
            for (int h = 0; h < 4; h++) {
                #pragma unroll
                for (int q = 0; q < 4; q++) {
                    s4[h] += acc[h * 4 + q][r] * asr[h * 4 + q];
                    d4[h] += acc[h * 4 + q][r] * adr[h * 4 + q];
                }
            }
            #pragma unroll
            for (int msk = 1; msk <= 8; msk <<= 1) {
                #pragma unroll
                for (int h = 0; h < 4; h++) {
                    s4[h] += __shfl_xor(s4[h], msk, 64);
                    d4[h] += __shfl_xor(d4[h], msk, 64);
                }
            }
            if (cl == 0 && n < Mrows) {
                *reinterpret_cast<float4*>(AS + (size_t)n * 4) =
                    make_float4(s4[0], s4[1], s4[2], s4[3]);
                *reinterpret_cast<float4*>(AD + (size_t)n * 4) =
                    make_float4(d4[0], d4[1], d4[2], d4[3]);
            }
        }
    }
}

// ---------------------------------------------------------------------------
// CSR build: zero -> count -> 3-phase parallel scan -> fill
// ---------------------------------------------------------------------------
__global__ __launch_bounds__(256) void zero_deg_k(int* __restrict__ deg)
{
    int i = blockIdx.x * 256 + threadIdx.x;
    if (i < NN) deg[i] = 0;
}

__global__ __launch_bounds__(256) void count_deg_k(const int* __restrict__ ei, int* __restrict__ deg)
{
    int e = blockIdx.x * 256 + threadIdx.x;
    if (e >= ETOT) return;
    int dst = (e < EE) ? ei[EE + e] : e - EE;
    atomicAdd(deg + dst, 1);
}

#define NB ((NN + 255) / 256)   // 196 scan blocks

__global__ __launch_bounds__(256) void bsum_k(const int* __restrict__ deg, int* __restrict__ bsum)
{
    __shared__ int red[4];
    int i = blockIdx.x * 256 + threadIdx.x;
    int v = (i < NN) ? deg[i] : 0;
    #pragma unroll
    for (int m = 32; m >= 1; m >>= 1) v += __shfl_xor(v, m, 64);
    if ((threadIdx.x & 63) == 0) red[threadIdx.x >> 6] = v;
    __syncthreads();
    if (threadIdx.x == 0) bsum[blockIdx.x] = red[0] + red[1] + red[2] + red[3];
}

__global__ __launch_bounds__(256) void bscan_k(int* __restrict__ bsum)
{
    __shared__ int tmp[256];
    int t = threadIdx.x;
    int v = (t < NB) ? bsum[t] : 0;
    tmp[t] = v;
    __syncthreads();
    #pragma unroll
    for (int off = 1; off < 256; off <<= 1) {
        int u = (t >= off) ? tmp[t - off] : 0;
        __syncthreads();
        tmp[t] += u;
        __syncthreads();
    }
    if (t < NB) bsum[t] = tmp[t] - v;   // exclusive prefix
}

__global__ __launch_bounds__(256) void rowptr_k(
    const int* __restrict__ deg, const int* __restrict__ bsum,
    int* __restrict__ rowptr, int* __restrict__ cursor)
{
    __shared__ int tmp[256];
    int t = threadIdx.x;
    int i = blockIdx.x * 256 + t;
    int v = (i < NN) ? deg[i] : 0;
    tmp[t] = v;
    __syncthreads();
    #pragma unroll
    for (int off = 1; off < 256; off <<= 1) {
        int u = (t >= off) ? tmp[t - off] : 0;
        __syncthreads();
        tmp[t] += u;
        __syncthreads();
    }
    int excl = tmp[t] - v + bsum[blockIdx.x];
    if (i < NN) { rowptr[i] = excl; cursor[i] = excl; }
    if (blockIdx.x == 0 && t == 0) rowptr[NN] = ETOT;
}

__global__ __launch_bounds__(256) void fill_k(
    const int* __restrict__ ei, int* __restrict__ cursor, int* __restrict__ EDG)
{
    int e = blockIdx.x * 256 + threadIdx.x;
    if (e >= ETOT) return;
    int src, dst;
    if (e < EE) { src = ei[e]; dst = ei[EE + e]; }
    else        { src = dst = e - EE; }
    int pos = atomicAdd(cursor + dst, 1);
    EDG[pos] = src;
}

// ---------------------------------------------------------------------------
// Single-pass gather-aggregate (softmax shift dropped: logits bounded, exp
// stays in fp32 range; softmax is shift-invariant).
// One wave per node (4/block). Lane l: feats l*4..l*4+3, head = l>>4.
// ---------------------------------------------------------------------------
template<int MODE>
__global__ __launch_bounds__(256) void gather_k(
    const int* __restrict__ rowptr, const int* __restrict__ EDG,
    const float* __restrict__ AS, const float* __restrict__ AD,
    const unsigned short* __restrict__ H, const float* __restrict__ bias,
    unsigned short* __restrict__ OUT, float* __restrict__ OUTF)
{
    __shared__ float wT[4][4][65];   // [wave][head][edge-in-chunk]
    int wid  = threadIdx.x >> 6;
    int lane = threadIdx.x & 63;
    int n = blockIdx.x * 4 + wid;
    if (n >= NN) return;
    int head = lane >> 4;

    int beg = rowptr[n], end = rowptr[n + 1];
    float4 ad4 = *reinterpret_cast<const float4*>(AD + (size_t)n * 4);

    float4 den4 = make_float4(0.f, 0.f, 0.f, 0.f);
    float a0 = 0.f, a1 = 0.f, a2 = 0.f, a3 = 0.f;
    const unsigned short* hp = H + lane * 4;

    for (int b = beg; b < end; b += 64) {
        int cd = min(end - b, 64);
        int srcv = (lane < cd) ? EDG[b + lane] : 0;
        float4 w4 = make_float4(0.f, 0.f, 0.f, 0.f);
        if (lane < cd) {
            float4 s4 = *reinterpret_cast<const float4*>(AS + (size_t)srcv * 4);
            w4.x = __expf(lrelu(s4.x + ad4.x));
            w4.y = __expf(lrelu(s4.y + ad4.y));
            w4.z = __expf(lrelu(s4.z + ad4.z));
            w4.w = __expf(lrelu(s4.w + ad4.w));
        }
        den4.x += w4.x; den4.y += w4.y; den4.z += w4.z; den4.w += w4.w;
        wT[wid][0][lane] = w4.x;
        wT[wid][1][lane] = w4.y;
        wT[wid][2][lane] = w4.z;
        wT[wid][3][lane] = w4.w;
        for (int j = 0; j < cd; j++) {
            int   src = __builtin_amdgcn_readlane(srcv, j);
            float wj  = wT[wid][head][j];
            ushort4 hv = *reinterpret_cast<const ushort4*>(hp + (size_t)src * 256);
            a0 += wj * b2f(hv.x); a1 += wj * b2f(hv.y);
            a2 += wj * b2f(hv.z); a3 += wj * b2f(hv.w);
        }
    }

    #pragma unroll
    for (int msk = 1; msk <= 32; msk <<= 1) {
        den4.x += __shfl_xor(den4.x, msk, 64);
        den4.y += __shfl_xor(den4.y, msk, 64);
        den4.z += __shfl_xor(den4.z, msk, 64);
        den4.w += __shfl_xor(den4.w, msk, 64);
    }
    float den = head == 0 ? den4.x : head == 1 ? den4.y : head == 2 ? den4.z : den4.w;
    float inv = 1.f / den;   // self-loop guarantees den > 0

    if (MODE == 1) {
        float4 bv = *reinterpret_cast<const float4*>(bias + lane * 4);
        ushort4 o;
        o.x = f2b(fmaxf(a0 * inv + bv.x, 0.f));
        o.y = f2b(fmaxf(a1 * inv + bv.y, 0.f));
        o.z = f2b(fmaxf(a2 * inv + bv.z, 0.f));
        o.w = f2b(fmaxf(a3 * inv + bv.w, 0.f));
        *reinterpret_cast<ushort4*>(OUT + (size_t)n * 256 + lane * 4) = o;
    } else {
        float v0 = a0 * inv, v1 = a1 * inv, v2 = a2 * inv, v3 = a3 * inv;
        #pragma unroll
        for (int msk = 16; msk <= 32; msk <<= 1) {
            v0 += __shfl_xor(v0, msk, 64);
            v1 += __shfl_xor(v1, msk, 64);
            v2 += __shfl_xor(v2, msk, 64);
            v3 += __shfl_xor(v3, msk, 64);
        }
        if (lane < 16) {
            float4* o = reinterpret_cast<float4*>(OUTF + (size_t)n * 64 + lane * 4);
            float4 cur = *o;
            cur.x += 0.25f * v0;
            cur.y += 0.25f * v1;
            cur.z += 0.25f * v2;
            cur.w += 0.25f * v3;
            *o = cur;
        }
    }
}

// ---------------------------------------------------------------------------
extern "C" void kernel_launch(void* const* d_in, const int* in_sizes, int n_in,
                              void* d_out, int out_size, void* d_ws, size_t ws_size,
                              hipStream_t stream) {
    const float* x    = (const float*)d_in[0];
    const float* root = (const float*)d_in[1];
    const int*   ei   = (const int*)  d_in[2];
    const float* W1   = (const float*)d_in[3];
    const float* as1  = (const float*)d_in[4];
    const float* ad1  = (const float*)d_in[5];
    const float* b1   = (const float*)d_in[6];
    const float* W2   = (const float*)d_in[7];
    const float* as2  = (const float*)d_in[8];
    const float* ad2  = (const float*)d_in[9];
    const float* b2   = (const float*)d_in[10];
    const float* Wr   = (const float*)d_in[11];
    const float* br   = (const float*)d_in[12];
    float* out = (float*)d_out;

    unsigned short* Hb  = (unsigned short*)d_ws;             // N*256
    unsigned short* X2b = Hb  + (size_t)NN * 256;            // N*256
    unsigned short* w1b = X2b + (size_t)NN * 256;            // 65536
    unsigned short* w2b = w1b + 65536;                       // 65536
    unsigned short* wrb = w2b + 65536;                       // 16384
    float* AS  = (float*)(wrb + 16384);                      // N*4
    float* AD  = AS + (size_t)NN * 4;                        // N*4
    int*   deg    = (int*)(AD + (size_t)NN * 4);             // N
    int*   rowptr = deg + NN;                                // N+1
    int*   cursor = rowptr + NN + 1;                         // N
    int*   bsum   = cursor + NN;                             // 256
    int*   EDG    = bsum + 256;                              // ETOT

    const int egrid = (ETOT + 255) / 256;
    const int ngrid = (NN + 255) / 256;
    const int wgrid = (NN + 3) / 4;
    const int mgrid = (NN + 63) / 64;

    // ----- CSR build -----
    zero_deg_k<<<ngrid, 256, 0, stream>>>(deg);
    count_deg_k<<<egrid, 256, 0, stream>>>(ei, deg);
    bsum_k<<<NB, 256, 0, stream>>>(deg, bsum);
    bscan_k<<<1, 256, 0, stream>>>(bsum);
    rowptr_k<<<NB, 256, 0, stream>>>(deg, bsum, rowptr, cursor);
    fill_k<<<egrid, 256, 0, stream>>>(ei, cursor, EDG);

    // ----- weight casts -----
    cast_k<<<(65536 / 4 + 255) / 256, 256, 0, stream>>>(W1, w1b, 65536);
    cast_k<<<(65536 / 4 + 255) / 256, 256, 0, stream>>>(W2, w2b, 65536);
    cast_k<<<(16384 / 4 + 255) / 256, 256, 0, stream>>>(Wr, wrb, 16384);

    // ----- layer 1: fp32 x -> bf16 H + fused AS/AD -----
    gemm_mfma<true, 16, true, false><<<mgrid, 256, 0, stream>>>(
        x, w1b, Hb, NN, as1, ad1, AS, AD, nullptr, nullptr);
    gather_k<1><<<wgrid, 256, 0, stream>>>(rowptr, EDG, AS, AD, Hb, b1, X2b, nullptr);

    // ----- layer 2: bf16 X2 -> bf16 H + fused AS/AD -----
    gemm_mfma<false, 16, true, false><<<mgrid, 256, 0, stream>>>(
        X2b, w2b, Hb, NN, as2, ad2, AS, AD, nullptr, nullptr);

    // ----- root skip (fp32 root -> fp32 out + br + b2), then head-mean add -----
    gemm_mfma<true, 4, false, true><<<mgrid, 256, 0, stream>>>(
        root, wrb, out, NN, nullptr, nullptr, nullptr, nullptr, br, b2);
    gather_k<2><<<wgrid, 256, 0, stream>>>(rowptr, EDG, AS, AD, Hb, nullptr, nullptr, out);
}

// Round 9
// 304.839 us; speedup vs baseline: 2.8928x; 1.0726x over previous
//
#include <hip/hip_runtime.h>
#include <hip/hip_bf16.h>
#include <math.h>

#define NN   50000
#define EE   800000
#define ETOT (EE + NN)
#define KDIM 256
#define HEADS 4
#define HIDD 64

typedef float  f32x4  __attribute__((ext_vector_type(4)));
typedef short  bf16x8 __attribute__((ext_vector_type(8)));

__device__ __forceinline__ float b2f(unsigned short u) {
    union { float f; unsigned int i; } v; v.i = (unsigned int)u << 16; return v.f;
}
__device__ __forceinline__ unsigned short f2b(float f) {
    union { float f; unsigned int i; } v; v.f = f;
    return (unsigned short)((v.i + 0x7fffu + ((v.i >> 16) & 1u)) >> 16);
}
__device__ __forceinline__ float lrelu(float x) { return x >= 0.f ? x : 0.2f * x; }

// ---------------------------------------------------------------------------
// prep_k: fused weight casts (W1,W2,Wr -> contiguous bf16) + deg zeroing.
// W1: 65536 elems, W2: 65536, Wr: 16384 -> 147456 = 36864 float4 = 144 blocks.
// Blocks 144.. : zero deg (50000 ints).
// ---------------------------------------------------------------------------
#define CASTB 144
#define PREPB (CASTB + (NN + 255) / 256)

__global__ __launch_bounds__(256) void prep_k(
    const float* __restrict__ W1, const float* __restrict__ W2,
    const float* __restrict__ Wr, unsigned short* __restrict__ wout,
    int* __restrict__ deg)
{
    int b = blockIdx.x;
    if (b < CASTB) {
        int i = (b * 256 + threadIdx.x) * 4;
        const float* src;
        int off;
        if (i < 65536)        { src = W1; off = 0; }
        else if (i < 131072)  { src = W2; off = 65536; }
        else                  { src = Wr; off = 131072; }
        float4 v = *reinterpret_cast<const float4*>(src + (i - off));
        ushort4 o;
        o.x = f2b(v.x); o.y = f2b(v.y); o.z = f2b(v.z); o.w = f2b(v.w);
        *reinterpret_cast<ushort4*>(wout + i) = o;
    } else {
        int i = (b - CASTB) * 256 + threadIdx.x;
        if (i < NN) deg[i] = 0;
    }
}

// ---------------------------------------------------------------------------
// Fused MFMA GEMM (TN), LDS-staged W, double-buffered K-slices of 32.
// C[m][c] = sum_k A[m][k]*W[c][k], K=256. Block: 4 waves x 16 rows = 64 rows.
// ---------------------------------------------------------------------------
template<bool AF32, int NCT, bool ALPHA, bool OUTF32>
__global__ __launch_bounds__(256) void gemm_mfma(
    const void* __restrict__ Ain, const unsigned short* __restrict__ W,
    void* __restrict__ Cout, int Mrows,
    const float* __restrict__ av_src, const float* __restrict__ av_dst,
    float* __restrict__ AS, float* __restrict__ AD,
    const float* __restrict__ bias0, const float* __restrict__ bias1)
{
    constexpr int ROWS = NCT * 16;
    constexpr int KS   = 32;
    constexpr int LDK  = 40;
    constexpr int NSL  = KDIM / KS;
    constexpr int NLD  = (ROWS * KS) / (256 * 8);
    __shared__ unsigned short Wl[2][ROWS][LDK];

    const int t    = threadIdx.x;
    const int wid  = t >> 6;
    const int lane = t & 63;
    const int cl   = lane & 15;
    const int kg   = lane >> 4;
    const int m0   = (blockIdx.x * 4 + wid) * 16;

    int arow = m0 + cl; if (arow >= Mrows) arow = Mrows - 1;

    bf16x8 stg[NLD];
    auto LOADSTG = [&](int s) {
        #pragma unroll
        for (int i = 0; i < NLD; i++) {
            int f = i * 256 + t;
            int c = f >> 2, kc = f & 3;
            stg[i] = *reinterpret_cast<const bf16x8*>(
                W + (size_t)c * KDIM + s * KS + kc * 8);
        }
    };
    auto WRITESTG = [&](int b) {
        #pragma unroll
        for (int i = 0; i < NLD; i++) {
            int f = i * 256 + t;
            int c = f >> 2, kc = f & 3;
            *reinterpret_cast<bf16x8*>(&Wl[b][c][kc * 8]) = stg[i];
        }
    };
    auto LOADA = [&](int s) -> bf16x8 {
        if constexpr (AF32) {
            const float* ap = (const float*)Ain + (size_t)arow * KDIM + s * KS + kg * 8;
            float4 v0 = *reinterpret_cast<const float4*>(ap);
            float4 v1 = *reinterpret_cast<const float4*>(ap + 4);
            bf16x8 a;
            a[0] = (short)f2b(v0.x); a[1] = (short)f2b(v0.y);
            a[2] = (short)f2b(v0.z); a[3] = (short)f2b(v0.w);
            a[4] = (short)f2b(v1.x); a[5] = (short)f2b(v1.y);
            a[6] = (short)f2b(v1.z); a[7] = (short)f2b(v1.w);
            return a;
        } else {
            return *reinterpret_cast<const bf16x8*>(
                (const unsigned short*)Ain + (size_t)arow * KDIM + s * KS + kg * 8);
        }
    };

    f32x4 acc[NCT];
    #pragma unroll
    for (int ct = 0; ct < NCT; ct++) acc[ct] = (f32x4)(0.f);

    LOADSTG(0);
    WRITESTG(0);
    bf16x8 a_cur = LOADA(0);
    __syncthreads();

    int buf = 0;
    for (int s = 0; s < NSL; s++) {
        bf16x8 a_nxt;
        if (s + 1 < NSL) { LOADSTG(s + 1); a_nxt = LOADA(s + 1); }
        #pragma unroll
        for (int ct = 0; ct < NCT; ct++) {
            bf16x8 b = *reinterpret_cast<const bf16x8*>(&Wl[buf][ct * 16 + cl][kg * 8]);
            acc[ct] = __builtin_amdgcn_mfma_f32_16x16x32_bf16(a_cur, b, acc[ct], 0, 0, 0);
        }
        if (s + 1 < NSL) {
            WRITESTG(buf ^ 1);
            __syncthreads();
            buf ^= 1;
            a_cur = a_nxt;
        }
    }

    if constexpr (OUTF32) {
        float* C = (float*)Cout;
        #pragma unroll
        for (int ct = 0; ct < NCT; ct++) {
            #pragma unroll
            for (int r = 0; r < 4; r++) {
                int n = m0 + kg * 4 + r;
                int c = ct * 16 + cl;
                if (n < Mrows)
                    C[(size_t)n * (NCT * 16) + c] = acc[ct][r] + bias0[c] + bias1[c];
            }
        }
    } else {
        unsigned short* C = (unsigned short*)Cout;
        #pragma unroll
        for (int ct = 0; ct < NCT; ct++) {
            #pragma unroll
            for (int r = 0; r < 4; r++) {
                int n = m0 + kg * 4 + r;
                if (n < Mrows)
                    C[(size_t)n * (NCT * 16) + ct * 16 + cl] = f2b(acc[ct][r]);
            }
        }
    }

    if constexpr (ALPHA) {
        float asr[NCT], adr[NCT];
        #pragma unroll
        for (int ct = 0; ct < NCT; ct++) {
            int c = ct * 16 + cl;
            asr[ct] = av_src[c];
            adr[ct] = av_dst[c];
        }
        #pragma unroll
        for (int r = 0; r < 4; r++) {
            int n = m0 + kg * 4 + r;
            f32x4 s4 = (f32x4)(0.f), d4 = (f32x4)(0.f);
            #pragma unroll
            for (int h = 0; h < 4; h++) {
                #pragma unroll
                for (int q = 0; q < 4; q++) {
                    s4[h] += acc[h * 4 + q][r] * asr[h * 4 + q];
                    d4[h] += acc[h * 4 + q][r] * adr[h * 4 + q];
                }
            }
            #pragma unroll
            for (int msk = 1; msk <= 8; msk <<= 1) {
                #pragma unroll
                for (int h = 0; h < 4; h++) {
                    s4[h] += __shfl_xor(s4[h], msk, 64);
                    d4[h] += __shfl_xor(d4[h], msk, 64);
                }
            }
            if (cl == 0 && n < Mrows) {
                *reinterpret_cast<float4*>(AS + (size_t)n * 4) =
                    make_float4(s4[0], s4[1], s4[2], s4[3]);
                *reinterpret_cast<float4*>(AD + (size_t)n * 4) =
                    make_float4(d4[0], d4[1], d4[2], d4[3]);
            }
        }
    }
}

// ---------------------------------------------------------------------------
// CSR build: count -> 3-phase parallel scan -> fill
// ---------------------------------------------------------------------------
__global__ __launch_bounds__(256) void count_deg_k(const int* __restrict__ ei, int* __restrict__ deg)
{
    int e = blockIdx.x * 256 + threadIdx.x;
    if (e >= ETOT) return;
    int dst = (e < EE) ? ei[EE + e] : e - EE;
    atomicAdd(deg + dst, 1);
}

#define NB ((NN + 255) / 256)   // 196 scan blocks

__global__ __launch_bounds__(256) void bsum_k(const int* __restrict__ deg, int* __restrict__ bsum)
{
    __shared__ int red[4];
    int i = blockIdx.x * 256 + threadIdx.x;
    int v = (i < NN) ? deg[i] : 0;
    #pragma unroll
    for (int m = 32; m >= 1; m >>= 1) v += __shfl_xor(v, m, 64);
    if ((threadIdx.x & 63) == 0) red[threadIdx.x >> 6] = v;
    __syncthreads();
    if (threadIdx.x == 0) bsum[blockIdx.x] = red[0] + red[1] + red[2] + red[3];
}

__global__ __launch_bounds__(256) void bscan_k(int* __restrict__ bsum)
{
    __shared__ int tmp[256];
    int t = threadIdx.x;
    int v = (t < NB) ? bsum[t] : 0;
    tmp[t] = v;
    __syncthreads();
    #pragma unroll
    for (int off = 1; off < 256; off <<= 1) {
        int u = (t >= off) ? tmp[t - off] : 0;
        __syncthreads();
        tmp[t] += u;
        __syncthreads();
    }
    if (t < NB) bsum[t] = tmp[t] - v;   // exclusive prefix
}

__global__ __launch_bounds__(256) void rowptr_k(
    const int* __restrict__ deg, const int* __restrict__ bsum,
    int* __restrict__ rowptr, int* __restrict__ cursor)
{
    __shared__ int tmp[256];
    int t = threadIdx.x;
    int i = blockIdx.x * 256 + t;
    int v = (i < NN) ? deg[i] : 0;
    tmp[t] = v;
    __syncthreads();
    #pragma unroll
    for (int off = 1; off < 256; off <<= 1) {
        int u = (t >= off) ? tmp[t - off] : 0;
        __syncthreads();
        tmp[t] += u;
        __syncthreads();
    }
    int excl = tmp[t] - v + bsum[blockIdx.x];
    if (i < NN) { rowptr[i] = excl; cursor[i] = excl; }
    if (blockIdx.x == 0 && t == 0) rowptr[NN] = ETOT;
}

__global__ __launch_bounds__(256) void fill_k(
    const int* __restrict__ ei, int* __restrict__ cursor, int* __restrict__ EDG)
{
    int e = blockIdx.x * 256 + threadIdx.x;
    if (e >= ETOT) return;
    int src, dst;
    if (e < EE) { src = ei[e]; dst = ei[EE + e]; }
    else        { src = dst = e - EE; }
    int pos = atomicAdd(cursor + dst, 1);
    EDG[pos] = src;
}

// ---------------------------------------------------------------------------
// Single-pass gather-aggregate. One wave per node (4/block).
// Lane l: feats l*4..l*4+3, head = l>>4. j-loop unrolled x2 with split
// accumulators: 2 H-rows in flight, halved FMA dependency chain.
// ---------------------------------------------------------------------------
template<int MODE>
__global__ __launch_bounds__(256) void gather_k(
    const int* __restrict__ rowptr, const int* __restrict__ EDG,
    const float* __restrict__ AS, const float* __restrict__ AD,
    const unsigned short* __restrict__ H, const float* __restrict__ bias,
    unsigned short* __restrict__ OUT, float* __restrict__ OUTF)
{
    __shared__ float wT[4][4][65];
    int wid  = threadIdx.x >> 6;
    int lane = threadIdx.x & 63;
    int n = blockIdx.x * 4 + wid;
    if (n >= NN) return;
    int head = lane >> 4;

    int beg = rowptr[n], end = rowptr[n + 1];
    float4 ad4 = *reinterpret_cast<const float4*>(AD + (size_t)n * 4);

    float4 den4 = make_float4(0.f, 0.f, 0.f, 0.f);
    float a0 = 0.f, a1 = 0.f, a2 = 0.f, a3 = 0.f;   // even edges
    float c0 = 0.f, c1 = 0.f, c2 = 0.f, c3 = 0.f;   // odd edges
    const unsigned short* hp = H + lane * 4;

    for (int b = beg; b < end; b += 64) {
        int cd = min(end - b, 64);
        int srcv = (lane < cd) ? EDG[b + lane] : 0;
        float4 w4 = make_float4(0.f, 0.f, 0.f, 0.f);
        if (lane < cd) {
            float4 s4 = *reinterpret_cast<const float4*>(AS + (size_t)srcv * 4);
            w4.x = __expf(lrelu(s4.x + ad4.x));
            w4.y = __expf(lrelu(s4.y + ad4.y));
            w4.z = __expf(lrelu(s4.z + ad4.z));
            w4.w = __expf(lrelu(s4.w + ad4.w));
        }
        den4.x += w4.x; den4.y += w4.y; den4.z += w4.z; den4.w += w4.w;
        wT[wid][0][lane] = w4.x;
        wT[wid][1][lane] = w4.y;
        wT[wid][2][lane] = w4.z;
        wT[wid][3][lane] = w4.w;
        int j = 0;
        for (; j + 2 <= cd; j += 2) {
            int   sA = __builtin_amdgcn_readlane(srcv, j);
            int   sB = __builtin_amdgcn_readlane(srcv, j + 1);
            float wA = wT[wid][head][j];
            float wB = wT[wid][head][j + 1];
            ushort4 hA = *reinterpret_cast<const ushort4*>(hp + (size_t)sA * 256);
            ushort4 hB = *reinterpret_cast<const ushort4*>(hp + (size_t)sB * 256);
            a0 += wA * b2f(hA.x); a1 += wA * b2f(hA.y);
            a2 += wA * b2f(hA.z); a3 += wA * b2f(hA.w);
            c0 += wB * b2f(hB.x); c1 += wB * b2f(hB.y);
            c2 += wB * b2f(hB.z); c3 += wB * b2f(hB.w);
        }
        if (j < cd) {
            int   sA = __builtin_amdgcn_readlane(srcv, j);
            float wA = wT[wid][head][j];
            ushort4 hA = *reinterpret_cast<const ushort4*>(hp + (size_t)sA * 256);
            a0 += wA * b2f(hA.x); a1 += wA * b2f(hA.y);
            a2 += wA * b2f(hA.z); a3 += wA * b2f(hA.w);
        }
    }
    a0 += c0; a1 += c1; a2 += c2; a3 += c3;

    #pragma unroll
    for (int msk = 1; msk <= 32; msk <<= 1) {
        den4.x += __shfl_xor(den4.x, msk, 64);
        den4.y += __shfl_xor(den4.y, msk, 64);
        den4.z += __shfl_xor(den4.z, msk, 64);
        den4.w += __shfl_xor(den4.w, msk, 64);
    }
    float den = head == 0 ? den4.x : head == 1 ? den4.y : head == 2 ? den4.z : den4.w;
    float inv = 1.f / den;   // self-loop guarantees den > 0

    if (MODE == 1) {
        float4 bv = *reinterpret_cast<const float4*>(bias + lane * 4);
        ushort4 o;
        o.x = f2b(fmaxf(a0 * inv + bv.x, 0.f));
        o.y = f2b(fmaxf(a1 * inv + bv.y, 0.f));
        o.z = f2b(fmaxf(a2 * inv + bv.z, 0.f));
        o.w = f2b(fmaxf(a3 * inv + bv.w, 0.f));
        *reinterpret_cast<ushort4*>(OUT + (size_t)n * 256 + lane * 4) = o;
    } else {
        float v0 = a0 * inv, v1 = a1 * inv, v2 = a2 * inv, v3 = a3 * inv;
        #pragma unroll
        for (int msk = 16; msk <= 32; msk <<= 1) {
            v0 += __shfl_xor(v0, msk, 64);
            v1 += __shfl_xor(v1, msk, 64);
            v2 += __shfl_xor(v2, msk, 64);
            v3 += __shfl_xor(v3, msk, 64);
        }
        if (lane < 16) {
            float4* o = reinterpret_cast<float4*>(OUTF + (size_t)n * 64 + lane * 4);
            float4 cur = *o;
            cur.x += 0.25f * v0;
            cur.y += 0.25f * v1;
            cur.z += 0.25f * v2;
            cur.w += 0.25f * v3;
            *o = cur;
        }
    }
}

// ---------------------------------------------------------------------------
extern "C" void kernel_launch(void* const* d_in, const int* in_sizes, int n_in,
                              void* d_out, int out_size, void* d_ws, size_t ws_size,
                              hipStream_t stream) {
    const float* x    = (const float*)d_in[0];
    const float* root = (const float*)d_in[1];
    const int*   ei   = (const int*)  d_in[2];
    const float* W1   = (const float*)d_in[3];
    const float* as1  = (const float*)d_in[4];
    const float* ad1  = (const float*)d_in[5];
    const float* b1   = (const float*)d_in[6];
    const float* W2   = (const float*)d_in[7];
    const float* as2  = (const float*)d_in[8];
    const float* ad2  = (const float*)d_in[9];
    const float* b2   = (const float*)d_in[10];
    const float* Wr   = (const float*)d_in[11];
    const float* br   = (const float*)d_in[12];
    float* out = (float*)d_out;

    unsigned short* Hb  = (unsigned short*)d_ws;             // N*256
    unsigned short* X2b = Hb  + (size_t)NN * 256;            // N*256
    unsigned short* w1b = X2b + (size_t)NN * 256;            // 65536
    unsigned short* w2b = w1b + 65536;                       // 65536
    unsigned short* wrb = w2b + 65536;                       // 16384
    float* AS  = (float*)(wrb + 16384);                      // N*4
    float* AD  = AS + (size_t)NN * 4;                        // N*4
    int*   deg    = (int*)(AD + (size_t)NN * 4);             // N
    int*   rowptr = deg + NN;                                // N+1
    int*   cursor = rowptr + NN + 1;                         // N
    int*   bsum   = cursor + NN;                             // 256
    int*   EDG    = bsum + 256;                              // ETOT

    const int egrid = (ETOT + 255) / 256;
    const int wgrid = (NN + 3) / 4;
    const int mgrid = (NN + 63) / 64;

    // ----- prep: weight casts + deg zero (fused) -----
    prep_k<<<PREPB, 256, 0, stream>>>(W1, W2, Wr, w1b, deg);

    // ----- CSR build -----
    count_deg_k<<<egrid, 256, 0, stream>>>(ei, deg);
    bsum_k<<<NB, 256, 0, stream>>>(deg, bsum);
    bscan_k<<<1, 256, 0, stream>>>(bsum);
    rowptr_k<<<NB, 256, 0, stream>>>(deg, bsum, rowptr, cursor);
    fill_k<<<egrid, 256, 0, stream>>>(ei, cursor, EDG);

    // ----- layer 1: fp32 x -> bf16 H + fused AS/AD -----
    gemm_mfma<true, 16, true, false><<<mgrid, 256, 0, stream>>>(
        x, w1b, Hb, NN, as1, ad1, AS, AD, nullptr, nullptr);
    gather_k<1><<<wgrid, 256, 0, stream>>>(rowptr, EDG, AS, AD, Hb, b1, X2b, nullptr);

    // ----- layer 2: bf16 X2 -> bf16 H + fused AS/AD -----
    gemm_mfma<false, 16, true, false><<<mgrid, 256, 0, stream>>>(
        X2b, w2b, Hb, NN, as2, ad2, AS, AD, nullptr, nullptr);

    // ----- root skip (fp32 root -> fp32 out + br + b2), then head-mean add -----
    gemm_mfma<true, 4, false, true><<<mgrid, 256, 0, stream>>>(
        root, wrb, out, NN, nullptr, nullptr, nullptr, nullptr, br, b2);
    gather_k<2><<<wgrid, 256, 0, stream>>>(rowptr, EDG, AS, AD, Hb, nullptr, nullptr, out);
}

// Round 10
// 304.035 us; speedup vs baseline: 2.9004x; 1.0026x over previous
//
#include <hip/hip_runtime.h>
#include <hip/hip_bf16.h>
#include <math.h>

#define NN   50000
#define EE   800000
#define ETOT (EE + NN)
#define KDIM 256
#define HEADS 4
#define HIDD 64

typedef float  f32x4  __attribute__((ext_vector_type(4)));
typedef short  bf16x8 __attribute__((ext_vector_type(8)));

__device__ __forceinline__ float b2f(unsigned short u) {
    union { float f; unsigned int i; } v; v.i = (unsigned int)u << 16; return v.f;
}
__device__ __forceinline__ unsigned short f2b(float f) {
    union { float f; unsigned int i; } v; v.f = f;
    return (unsigned short)((v.i + 0x7fffu + ((v.i >> 16) & 1u)) >> 16);
}
__device__ __forceinline__ float lrelu(float x) { return x >= 0.f ? x : 0.2f * x; }

// ---------------------------------------------------------------------------
// prep_k: fused weight casts (W1,W2,Wr -> contiguous bf16) + deg zeroing.
// ---------------------------------------------------------------------------
#define CASTB 144
#define PREPB (CASTB + (NN + 255) / 256)

__global__ __launch_bounds__(256) void prep_k(
    const float* __restrict__ W1, const float* __restrict__ W2,
    const float* __restrict__ Wr, unsigned short* __restrict__ wout,
    int* __restrict__ deg)
{
    int b = blockIdx.x;
    if (b < CASTB) {
        int i = (b * 256 + threadIdx.x) * 4;
        const float* src;
        int off;
        if (i < 65536)        { src = W1; off = 0; }
        else if (i < 131072)  { src = W2; off = 65536; }
        else                  { src = Wr; off = 131072; }
        float4 v = *reinterpret_cast<const float4*>(src + (i - off));
        ushort4 o;
        o.x = f2b(v.x); o.y = f2b(v.y); o.z = f2b(v.z); o.w = f2b(v.w);
        *reinterpret_cast<ushort4*>(wout + i) = o;
    } else {
        int i = (b - CASTB) * 256 + threadIdx.x;
        if (i < NN) deg[i] = 0;
    }
}

// ---------------------------------------------------------------------------
// Fused MFMA GEMM (TN), LDS-staged W, double-buffered K-slices of 32.
// ---------------------------------------------------------------------------
template<bool AF32, int NCT, bool ALPHA, bool OUTF32>
__global__ __launch_bounds__(256) void gemm_mfma(
    const void* __restrict__ Ain, const unsigned short* __restrict__ W,
    void* __restrict__ Cout, int Mrows,
    const float* __restrict__ av_src, const float* __restrict__ av_dst,
    float* __restrict__ AS, float* __restrict__ AD,
    const float* __restrict__ bias0, const float* __restrict__ bias1)
{
    constexpr int ROWS = NCT * 16;
    constexpr int KS   = 32;
    constexpr int LDK  = 40;
    constexpr int NSL  = KDIM / KS;
    constexpr int NLD  = (ROWS * KS) / (256 * 8);
    __shared__ unsigned short Wl[2][ROWS][LDK];

    const int t    = threadIdx.x;
    const int wid  = t >> 6;
    const int lane = t & 63;
    const int cl   = lane & 15;
    const int kg   = lane >> 4;
    const int m0   = (blockIdx.x * 4 + wid) * 16;

    int arow = m0 + cl; if (arow >= Mrows) arow = Mrows - 1;

    bf16x8 stg[NLD];
    auto LOADSTG = [&](int s) {
        #pragma unroll
        for (int i = 0; i < NLD; i++) {
            int f = i * 256 + t;
            int c = f >> 2, kc = f & 3;
            stg[i] = *reinterpret_cast<const bf16x8*>(
                W + (size_t)c * KDIM + s * KS + kc * 8);
        }
    };
    auto WRITESTG = [&](int b) {
        #pragma unroll
        for (int i = 0; i < NLD; i++) {
            int f = i * 256 + t;
            int c = f >> 2, kc = f & 3;
            *reinterpret_cast<bf16x8*>(&Wl[b][c][kc * 8]) = stg[i];
        }
    };
    auto LOADA = [&](int s) -> bf16x8 {
        if constexpr (AF32) {
            const float* ap = (const float*)Ain + (size_t)arow * KDIM + s * KS + kg * 8;
            float4 v0 = *reinterpret_cast<const float4*>(ap);
            float4 v1 = *reinterpret_cast<const float4*>(ap + 4);
            bf16x8 a;
            a[0] = (short)f2b(v0.x); a[1] = (short)f2b(v0.y);
            a[2] = (short)f2b(v0.z); a[3] = (short)f2b(v0.w);
            a[4] = (short)f2b(v1.x); a[5] = (short)f2b(v1.y);
            a[6] = (short)f2b(v1.z); a[7] = (short)f2b(v1.w);
            return a;
        } else {
            return *reinterpret_cast<const bf16x8*>(
                (const unsigned short*)Ain + (size_t)arow * KDIM + s * KS + kg * 8);
        }
    };

    f32x4 acc[NCT];
    #pragma unroll
    for (int ct = 0; ct < NCT; ct++) acc[ct] = (f32x4)(0.f);

    LOADSTG(0);
    WRITESTG(0);
    bf16x8 a_cur = LOADA(0);
    __syncthreads();

    int buf = 0;
    for (int s = 0; s < NSL; s++) {
        bf16x8 a_nxt;
        if (s + 1 < NSL) { LOADSTG(s + 1); a_nxt = LOADA(s + 1); }
        #pragma unroll
        for (int ct = 0; ct < NCT; ct++) {
            bf16x8 b = *reinterpret_cast<const bf16x8*>(&Wl[buf][ct * 16 + cl][kg * 8]);
            acc[ct] = __builtin_amdgcn_mfma_f32_16x16x32_bf16(a_cur, b, acc[ct], 0, 0, 0);
        }
        if (s + 1 < NSL) {
            WRITESTG(buf ^ 1);
            __syncthreads();
            buf ^= 1;
            a_cur = a_nxt;
        }
    }

    if constexpr (OUTF32) {
        float* C = (float*)Cout;
        #pragma unroll
        for (int ct = 0; ct < NCT; ct++) {
            #pragma unroll
            for (int r = 0; r < 4; r++) {
                int n = m0 + kg * 4 + r;
                int c = ct * 16 + cl;
                if (n < Mrows)
                    C[(size_t)n * (NCT * 16) + c] = acc[ct][r] + bias0[c] + bias1[c];
            }
        }
    } else {
        unsigned short* C = (unsigned short*)Cout;
        #pragma unroll
        for (int ct = 0; ct < NCT; ct++) {
            #pragma unroll
            for (int r = 0; r < 4; r++) {
                int n = m0 + kg * 4 + r;
                if (n < Mrows)
                    C[(size_t)n * (NCT * 16) + ct * 16 + cl] = f2b(acc[ct][r]);
            }
        }
    }

    if constexpr (ALPHA) {
        float asr[NCT], adr[NCT];
        #pragma unroll
        for (int ct = 0; ct < NCT; ct++) {
            int c = ct * 16 + cl;
            asr[ct] = av_src[c];
            adr[ct] = av_dst[c];
        }
        #pragma unroll
        for (int r = 0; r < 4; r++) {
            int n = m0 + kg * 4 + r;
            f32x4 s4 = (f32x4)(0.f), d4 = (f32x4)(0.f);
            #pragma unroll
            for (int h = 0; h < 4; h++) {
                #pragma unroll
                for (int q = 0; q < 4; q++) {
                    s4[h] += acc[h * 4 + q][r] * asr[h * 4 + q];
                    d4[h] += acc[h * 4 + q][r] * adr[h * 4 + q];
                }
            }
            #pragma unroll
            for (int msk = 1; msk <= 8; msk <<= 1) {
                #pragma unroll
                for (int h = 0; h < 4; h++) {
                    s4[h] += __shfl_xor(s4[h], msk, 64);
                    d4[h] += __shfl_xor(d4[h], msk, 64);
                }
            }
            if (cl == 0 && n < Mrows) {
                *reinterpret_cast<float4*>(AS + (size_t)n * 4) =
                    make_float4(s4[0], s4[1], s4[2], s4[3]);
                *reinterpret_cast<float4*>(AD + (size_t)n * 4) =
                    make_float4(d4[0], d4[1], d4[2], d4[3]);
            }
        }
    }
}

// ---------------------------------------------------------------------------
// CSR build: count -> 3-phase parallel scan -> fill
// ---------------------------------------------------------------------------
__global__ __launch_bounds__(256) void count_deg_k(const int* __restrict__ ei, int* __restrict__ deg)
{
    int e = blockIdx.x * 256 + threadIdx.x;
    if (e >= ETOT) return;
    int dst = (e < EE) ? ei[EE + e] : e - EE;
    atomicAdd(deg + dst, 1);
}

#define NB ((NN + 255) / 256)   // 196 scan blocks

__global__ __launch_bounds__(256) void bsum_k(const int* __restrict__ deg, int* __restrict__ bsum)
{
    __shared__ int red[4];
    int i = blockIdx.x * 256 + threadIdx.x;
    int v = (i < NN) ? deg[i] : 0;
    #pragma unroll
    for (int m = 32; m >= 1; m >>= 1) v += __shfl_xor(v, m, 64);
    if ((threadIdx.x & 63) == 0) red[threadIdx.x >> 6] = v;
    __syncthreads();
    if (threadIdx.x == 0) bsum[blockIdx.x] = red[0] + red[1] + red[2] + red[3];
}

__global__ __launch_bounds__(256) void bscan_k(int* __restrict__ bsum)
{
    __shared__ int tmp[256];
    int t = threadIdx.x;
    int v = (t < NB) ? bsum[t] : 0;
    tmp[t] = v;
    __syncthreads();
    #pragma unroll
    for (int off = 1; off < 256; off <<= 1) {
        int u = (t >= off) ? tmp[t - off] : 0;
        __syncthreads();
        tmp[t] += u;
        __syncthreads();
    }
    if (t < NB) bsum[t] = tmp[t] - v;   // exclusive prefix
}

__global__ __launch_bounds__(256) void rowptr_k(
    const int* __restrict__ deg, const int* __restrict__ bsum,
    int* __restrict__ rowptr, int* __restrict__ cursor)
{
    __shared__ int tmp[256];
    int t = threadIdx.x;
    int i = blockIdx.x * 256 + t;
    int v = (i < NN) ? deg[i] : 0;
    tmp[t] = v;
    __syncthreads();
    #pragma unroll
    for (int off = 1; off < 256; off <<= 1) {
        int u = (t >= off) ? tmp[t - off] : 0;
        __syncthreads();
        tmp[t] += u;
        __syncthreads();
    }
    int excl = tmp[t] - v + bsum[blockIdx.x];
    if (i < NN) { rowptr[i] = excl; cursor[i] = excl; }
    if (blockIdx.x == 0 && t == 0) rowptr[NN] = ETOT;
}

__global__ __launch_bounds__(256) void fill_k(
    const int* __restrict__ ei, int* __restrict__ cursor, int* __restrict__ EDG)
{
    int e = blockIdx.x * 256 + threadIdx.x;
    if (e >= ETOT) return;
    int src, dst;
    if (e < EE) { src = ei[e]; dst = ei[EE + e]; }
    else        { src = dst = e - EE; }
    int pos = atomicAdd(cursor + dst, 1);
    EDG[pos] = src;
}

// ---------------------------------------------------------------------------
// Single-pass gather-aggregate. One wave per node (4/block).
// Lane l: feats l*4..l*4+3, head = l>>4. j-loop unrolled x4: four independent
// H-row loads in flight per iteration, two accumulator sets (halved FMA chain).
// ---------------------------------------------------------------------------
template<int MODE>
__global__ __launch_bounds__(256) void gather_k(
    const int* __restrict__ rowptr, const int* __restrict__ EDG,
    const float* __restrict__ AS, const float* __restrict__ AD,
    const unsigned short* __restrict__ H, const float* __restrict__ bias,
    unsigned short* __restrict__ OUT, float* __restrict__ OUTF)
{
    __shared__ float wT[4][4][65];
    int wid  = threadIdx.x >> 6;
    int lane = threadIdx.x & 63;
    int n = blockIdx.x * 4 + wid;
    if (n >= NN) return;
    int head = lane >> 4;

    int beg = rowptr[n], end = rowptr[n + 1];
    float4 ad4 = *reinterpret_cast<const float4*>(AD + (size_t)n * 4);

    float4 den4 = make_float4(0.f, 0.f, 0.f, 0.f);
    float a0 = 0.f, a1 = 0.f, a2 = 0.f, a3 = 0.f;   // acc set A
    float c0 = 0.f, c1 = 0.f, c2 = 0.f, c3 = 0.f;   // acc set B
    const unsigned short* hp = H + lane * 4;

    for (int b = beg; b < end; b += 64) {
        int cd = min(end - b, 64);
        int srcv = (lane < cd) ? EDG[b + lane] : 0;
        float4 w4 = make_float4(0.f, 0.f, 0.f, 0.f);
        if (lane < cd) {
            float4 s4 = *reinterpret_cast<const float4*>(AS + (size_t)srcv * 4);
            w4.x = __expf(lrelu(s4.x + ad4.x));
            w4.y = __expf(lrelu(s4.y + ad4.y));
            w4.z = __expf(lrelu(s4.z + ad4.z));
            w4.w = __expf(lrelu(s4.w + ad4.w));
        }
        den4.x += w4.x; den4.y += w4.y; den4.z += w4.z; den4.w += w4.w;
        wT[wid][0][lane] = w4.x;
        wT[wid][1][lane] = w4.y;
        wT[wid][2][lane] = w4.z;
        wT[wid][3][lane] = w4.w;
        int j = 0;
        for (; j + 4 <= cd; j += 4) {
            int   sA = __builtin_amdgcn_readlane(srcv, j);
            int   sB = __builtin_amdgcn_readlane(srcv, j + 1);
            int   sC = __builtin_amdgcn_readlane(srcv, j + 2);
            int   sD = __builtin_amdgcn_readlane(srcv, j + 3);
            float wA = wT[wid][head][j];
            float wB = wT[wid][head][j + 1];
            float wC = wT[wid][head][j + 2];
            float wD = wT[wid][head][j + 3];
            ushort4 hA = *reinterpret_cast<const ushort4*>(hp + (size_t)sA * 256);
            ushort4 hB = *reinterpret_cast<const ushort4*>(hp + (size_t)sB * 256);
            ushort4 hC = *reinterpret_cast<const ushort4*>(hp + (size_t)sC * 256);
            ushort4 hD = *reinterpret_cast<const ushort4*>(hp + (size_t)sD * 256);
            a0 += wA * b2f(hA.x); a1 += wA * b2f(hA.y);
            a2 += wA * b2f(hA.z); a3 += wA * b2f(hA.w);
            c0 += wB * b2f(hB.x); c1 += wB * b2f(hB.y);
            c2 += wB * b2f(hB.z); c3 += wB * b2f(hB.w);
            a0 += wC * b2f(hC.x); a1 += wC * b2f(hC.y);
            a2 += wC * b2f(hC.z); a3 += wC * b2f(hC.w);
            c0 += wD * b2f(hD.x); c1 += wD * b2f(hD.y);
            c2 += wD * b2f(hD.z); c3 += wD * b2f(hD.w);
        }
        for (; j < cd; j++) {
            int   sA = __builtin_amdgcn_readlane(srcv, j);
            float wA = wT[wid][head][j];
            ushort4 hA = *reinterpret_cast<const ushort4*>(hp + (size_t)sA * 256);
            a0 += wA * b2f(hA.x); a1 += wA * b2f(hA.y);
            a2 += wA * b2f(hA.z); a3 += wA * b2f(hA.w);
        }
    }
    a0 += c0; a1 += c1; a2 += c2; a3 += c3;

    #pragma unroll
    for (int msk = 1; msk <= 32; msk <<= 1) {
        den4.x += __shfl_xor(den4.x, msk, 64);
        den4.y += __shfl_xor(den4.y, msk, 64);
        den4.z += __shfl_xor(den4.z, msk, 64);
        den4.w += __shfl_xor(den4.w, msk, 64);
    }
    float den = head == 0 ? den4.x : head == 1 ? den4.y : head == 2 ? den4.z : den4.w;
    float inv = 1.f / den;   // self-loop guarantees den > 0

    if (MODE == 1) {
        float4 bv = *reinterpret_cast<const float4*>(bias + lane * 4);
        ushort4 o;
        o.x = f2b(fmaxf(a0 * inv + bv.x, 0.f));
        o.y = f2b(fmaxf(a1 * inv + bv.y, 0.f));
        o.z = f2b(fmaxf(a2 * inv + bv.z, 0.f));
        o.w = f2b(fmaxf(a3 * inv + bv.w, 0.f));
        *reinterpret_cast<ushort4*>(OUT + (size_t)n * 256 + lane * 4) = o;
    } else {
        float v0 = a0 * inv, v1 = a1 * inv, v2 = a2 * inv, v3 = a3 * inv;
        #pragma unroll
        for (int msk = 16; msk <= 32; msk <<= 1) {
            v0 += __shfl_xor(v0, msk, 64);
            v1 += __shfl_xor(v1, msk, 64);
            v2 += __shfl_xor(v2, msk, 64);
            v3 += __shfl_xor(v3, msk, 64);
        }
        if (lane < 16) {
            float4* o = reinterpret_cast<float4*>(OUTF + (size_t)n * 64 + lane * 4);
            float4 cur = *o;
            cur.x += 0.25f * v0;
            cur.y += 0.25f * v1;
            cur.z += 0.25f * v2;
            cur.w += 0.25f * v3;
            *o = cur;
        }
    }
}

// ---------------------------------------------------------------------------
extern "C" void kernel_launch(void* const* d_in, const int* in_sizes, int n_in,
                              void* d_out, int out_size, void* d_ws, size_t ws_size,
                              hipStream_t stream) {
    const float* x    = (const float*)d_in[0];
    const float* root = (const float*)d_in[1];
    const int*   ei   = (const int*)  d_in[2];
    const float* W1   = (const float*)d_in[3];
    const float* as1  = (const float*)d_in[4];
    const float* ad1  = (const float*)d_in[5];
    const float* b1   = (const float*)d_in[6];
    const float* W2   = (const float*)d_in[7];
    const float* as2  = (const float*)d_in[8];
    const float* ad2  = (const float*)d_in[9];
    const float* b2   = (const float*)d_in[10];
    const float* Wr   = (const float*)d_in[11];
    const float* br   = (const float*)d_in[12];
    float* out = (float*)d_out;

    unsigned short* Hb  = (unsigned short*)d_ws;             // N*256
    unsigned short* X2b = Hb  + (size_t)NN * 256;            // N*256
    unsigned short* w1b = X2b + (size_t)NN * 256;            // 65536
    unsigned short* w2b = w1b + 65536;                       // 65536
    unsigned short* wrb = w2b + 65536;                       // 16384
    float* AS  = (float*)(wrb + 16384);                      // N*4
    float* AD  = AS + (size_t)NN * 4;                        // N*4
    int*   deg    = (int*)(AD + (size_t)NN * 4);             // N
    int*   rowptr = deg + NN;                                // N+1
    int*   cursor = rowptr + NN + 1;                         // N
    int*   bsum   = cursor + NN;                             // 256
    int*   EDG    = bsum + 256;                              // ETOT

    const int egrid = (ETOT + 255) / 256;
    const int wgrid = (NN + 3) / 4;
    const int mgrid = (NN + 63) / 64;

    // ----- prep: weight casts + deg zero (fused) -----
    prep_k<<<PREPB, 256, 0, stream>>>(W1, W2, Wr, w1b, deg);

    // ----- CSR build -----
    count_deg_k<<<egrid, 256, 0, stream>>>(ei, deg);
    bsum_k<<<NB, 256, 0, stream>>>(deg, bsum);
    bscan_k<<<1, 256, 0, stream>>>(bsum);
    rowptr_k<<<NB, 256, 0, stream>>>(deg, bsum, rowptr, cursor);
    fill_k<<<egrid, 256, 0, stream>>>(ei, cursor, EDG);

    // ----- layer 1: fp32 x -> bf16 H + fused AS/AD -----
    gemm_mfma<true, 16, true, false><<<mgrid, 256, 0, stream>>>(
        x, w1b, Hb, NN, as1, ad1, AS, AD, nullptr, nullptr);
    gather_k<1><<<wgrid, 256, 0, stream>>>(rowptr, EDG, AS, AD, Hb, b1, X2b, nullptr);

    // ----- layer 2: bf16 X2 -> bf16 H + fused AS/AD -----
    gemm_mfma<false, 16, true, false><<<mgrid, 256, 0, stream>>>(
        X2b, w2b, Hb, NN, as2, ad2, AS, AD, nullptr, nullptr);

    // ----- root skip (fp32 root -> fp32 out + br + b2), then head-mean add -----
    gemm_mfma<true, 4, false, true><<<mgrid, 256, 0, stream>>>(
        root, wrb, out, NN, nullptr, nullptr, nullptr, nullptr, br, b2);
    gather_k<2><<<wgrid, 256, 0, stream>>>(rowptr, EDG, AS, AD, Hb, nullptr, nullptr, out);
}